// Round 4
// baseline (136.429 us; speedup 1.0000x reference)
//
#include <hip/hip_runtime.h>
#include <math.h>

#define B_SZ 1024
#define Z_DIM 512
#define A_DIM 8
#define AH 64
#define ZH 512
#define NNEG 99
#define INV_T 10.0f

typedef __attribute__((ext_vector_type(8))) short short8;   // 8 bf16 (16 B)
typedef __attribute__((ext_vector_type(4))) float f32x4;

// fp32 -> bf16 round-to-nearest-even (unbiased; rel err <= 2^-9)
__device__ __forceinline__ short bf16rn(float x) {
    unsigned u = __float_as_uint(x);
    u += 0x7fffu + ((u >> 16) & 1u);
    return (short)(u >> 16);
}
__device__ __forceinline__ void cvt8rn(float4 x0, float4 x1, short8& h) {
    h[0] = bf16rn(x0.x); h[1] = bf16rn(x0.y); h[2] = bf16rn(x0.z); h[3] = bf16rn(x0.w);
    h[4] = bf16rn(x1.x); h[5] = bf16rn(x1.y); h[6] = bf16rn(x1.z); h[7] = bf16rn(x1.w);
}

// XOR-swizzled 16B-unit index into a [64 rows][8 units] bf16 tile (no padding).
__device__ __forceinline__ int sw(int m, int kb) { return m * 8 + (kb ^ (m & 7)); }

// ---------------------------------------------------------------------------
// prep: blocks [0,72) transpose W1 [576][512] -> W1T [512][576];
//       blocks [72,88) compute ha = relu(actions@Wa+ba)  [1024][64];
//       block 0 resets cnt.
__global__ __launch_bounds__(256) void prep_kernel(
    const float* __restrict__ W1, const float* __restrict__ actions,
    const float* __restrict__ Wa, const float* __restrict__ ba,
    float* __restrict__ W1T, float* __restrict__ ha, unsigned* __restrict__ cnt)
{
    const int id = blockIdx.x, tid = threadIdx.x;
    if (id == 0 && tid == 0) atomicExch(cnt, 0u);
    if (id < 72) {
        __shared__ float L[64][68];
        int kt = id >> 3, nt = id & 7;
#pragma unroll
        for (int i = 0; i < 4; ++i) {
            int f = tid + i * 256;
            int r = f >> 4, c4 = (f & 15) << 2;
            *(float4*)&L[r][c4] = *(const float4*)&W1[(kt * 64 + r) * 512 + nt * 64 + c4];
        }
        __syncthreads();
#pragma unroll
        for (int i = 0; i < 4; ++i) {
            int f = tid + i * 256;
            int r = f >> 4, c4 = (f & 15) << 2;
            float4 o = {L[c4][r], L[c4 + 1][r], L[c4 + 2][r], L[c4 + 3][r]};
            *(float4*)&W1T[(nt * 64 + r) * 576 + kt * 64 + c4] = o;
        }
    } else if (id < 88) {
        __shared__ float sWa[A_DIM * 64];
        __shared__ float sba[64];
        __shared__ float sact[64][A_DIM];
        int j0 = (id - 72) * 64;
        for (int i = tid; i < A_DIM * 64; i += 256) sWa[i] = Wa[i];
        if (tid < 64) sba[tid] = ba[tid];
        for (int i = tid; i < 64 * A_DIM; i += 256) (&sact[0][0])[i] = actions[j0 * A_DIM + i];
        __syncthreads();
        int r = tid >> 2, c0 = (tid & 3) * 16;
        float o[16];
#pragma unroll
        for (int c = 0; c < 16; ++c) o[c] = sba[c0 + c];
#pragma unroll
        for (int k = 0; k < A_DIM; ++k) {
            float a = sact[r][k];
#pragma unroll
            for (int c = 0; c < 16; ++c) o[c] += a * sWa[k * 64 + c0 + c];
        }
#pragma unroll
        for (int c = 0; c < 16; c += 4) {
            float4 v4 = {fmaxf(o[c], 0.f), fmaxf(o[c + 1], 0.f),
                         fmaxf(o[c + 2], 0.f), fmaxf(o[c + 3], 0.f)};
            *(float4*)&ha[(j0 + r) * 64 + c0 + c] = v4;
        }
    }
}

// ---------------------------------------------------------------------------
// Uniform NT MFMA GEMM, 640 blocks, plain bf16 (RN conversion at staging):
//   seg0 [  0,256): sim = z_next @ z_next_hat^T [1024x1024 K=512]
//   seg1 [256,384): u   = z @ W1T[:, :512]^T+b1 [1024x512  K=512]
//   seg2 [384,512): v   = z_next @ W2^T         [1024x512  K=512]
//   seg3 [512,640): g   = ha @ W1T[:,512:]^T    [1024x512  K=64]
__global__ __launch_bounds__(256) void mm_kernel(
    const float* __restrict__ z, const float* __restrict__ z_next,
    const float* __restrict__ z_next_hat, const float* __restrict__ W1T,
    const float* __restrict__ b1, const float* __restrict__ W2,
    const float* __restrict__ ha,
    float* __restrict__ sim, float* __restrict__ u, float* __restrict__ v,
    float* __restrict__ g)
{
    __shared__ short Ah[4096], Bh[4096];   // 16 KB

    const int id = blockIdx.x;
    const int tid = threadIdx.x;

    const float* Aop; const float* Bop; const float* bias = nullptr;
    float* C; int N, K, lda, ldb, bm0, bn0;
    if (id < 256) {
        int t = id; bn0 = (t & 15) * 64; bm0 = (t >> 4) * 64;
        Aop = z_next; lda = 512; Bop = z_next_hat; ldb = 512;
        C = sim; N = 1024; K = 512;
    } else if (id < 384) {
        int t = id - 256; bn0 = (t & 7) * 64; bm0 = (t >> 3) * 64;
        Aop = z; lda = 512; Bop = W1T; ldb = 576;
        C = u; N = 512; K = 512; bias = b1;
    } else if (id < 512) {
        int t = id - 384; bn0 = (t & 7) * 64; bm0 = (t >> 3) * 64;
        Aop = z_next; lda = 512; Bop = W2; ldb = 512;
        C = v; N = 512; K = 512;
    } else {
        int t = id - 512; bn0 = (t & 7) * 64; bm0 = (t >> 3) * 64;
        Aop = ha; lda = 64; Bop = W1T + 512; ldb = 576;
        C = g; N = 512; K = 64;
    }

    const int lane = tid & 63, wv = tid >> 6;
    const int lm = lane & 15, lq = lane >> 4;
    const int wm = (wv >> 1) * 32, wn = (wv & 1) * 32;
    const int sr = tid >> 2, sq = tid & 3;     // staging: row, 16-float quarter
    short8* Ah8 = (short8*)Ah; short8* Bh8 = (short8*)Bh;
    f32x4 acc[2][2] = {};

    for (int k0 = 0; k0 < K; k0 += 64) {
        {   // A: 16 consecutive floats of row sr -> units 2sq, 2sq+1
            const float* base = &Aop[(bm0 + sr) * lda + k0 + sq * 16];
            float4 x0 = *(const float4*)(base + 0), x1 = *(const float4*)(base + 4);
            float4 x2 = *(const float4*)(base + 8), x3 = *(const float4*)(base + 12);
            short8 h;
            cvt8rn(x0, x1, h); Ah8[sw(sr, 2 * sq)] = h;
            cvt8rn(x2, x3, h); Ah8[sw(sr, 2 * sq + 1)] = h;
        }
        {   // B: same, NT layout
            const float* base = &Bop[(bn0 + sr) * ldb + k0 + sq * 16];
            float4 x0 = *(const float4*)(base + 0), x1 = *(const float4*)(base + 4);
            float4 x2 = *(const float4*)(base + 8), x3 = *(const float4*)(base + 12);
            short8 h;
            cvt8rn(x0, x1, h); Bh8[sw(sr, 2 * sq)] = h;
            cvt8rn(x2, x3, h); Bh8[sw(sr, 2 * sq + 1)] = h;
        }
        __syncthreads();
#pragma unroll
        for (int kk = 0; kk < 64; kk += 32) {
            int kbi = (kk >> 3) + lq;
            short8 ah[2], bh[2];
#pragma unroll
            for (int i = 0; i < 2; ++i) {
                ah[i] = Ah8[sw(wm + i * 16 + lm, kbi)];
                bh[i] = Bh8[sw(wn + i * 16 + lm, kbi)];
            }
#pragma unroll
            for (int i = 0; i < 2; ++i)
#pragma unroll
                for (int j = 0; j < 2; ++j)
                    acc[i][j] = __builtin_amdgcn_mfma_f32_16x16x32_bf16(ah[i], bh[j], acc[i][j], 0, 0, 0);
        }
        __syncthreads();
    }
    // epilogue: C layout col=lane&15, row=(lane>>4)*4+reg
#pragma unroll
    for (int i = 0; i < 2; ++i)
#pragma unroll
        for (int j = 0; j < 2; ++j) {
            int n = bn0 + wn + j * 16 + lm;
            float bb = bias ? bias[n] : 0.0f;
#pragma unroll
            for (int r = 0; r < 4; ++r) {
                int m = bm0 + wm + i * 16 + lq * 4 + r;
                C[m * N + n] = acc[i][j][r] + bb;
            }
        }
}

// ---------------------------------------------------------------------------
// row2 v5: async-staged pipeline. Evidence from R0/R1/R3: three structurally
// different row2 versions all pinned at ~43 us, VALUBusy ~12%, HBM ~4% =>
// effective ONE outstanding load per wave (compiler serializes register
// buffers; __syncthreads drains vmcnt(0)). Fix the compiler can't defeat:
// __builtin_amdgcn_global_load_lds (no VGPR dest to serialize) + hand-counted
// s_waitcnt vmcnt(4) + RAW s_barrier (no implicit vmcnt(0) drain), double-
// buffered 8-row chunks (2x16KB LDS). Prefetch of chunk c+1 stays in flight
// across the barrier while chunk c is consumed -> pipeline period = 1 HBM
// latency, 13 chunks + 4 blocks/CU concurrency.
#define VMWAIT(N) asm volatile("s_waitcnt vmcnt(" #N ")" ::: "memory")
__device__ __forceinline__ void raw_barrier() {
    asm volatile("" ::: "memory");
    __builtin_amdgcn_s_barrier();
    asm volatile("" ::: "memory");
}
typedef const __attribute__((address_space(1))) void* gas_ptr;
typedef __attribute__((address_space(3))) void* las_ptr;
__device__ __forceinline__ void gld_lds16(const float* gsrc, float* ldst) {
    __builtin_amdgcn_global_load_lds((gas_ptr)gsrc, (las_ptr)ldst, 16, 0, 0);
}

__global__ __launch_bounds__(256, 4) void row2_kernel(
    const float* __restrict__ sim, const float* __restrict__ u,
    const float* __restrict__ v, const float* __restrict__ g,
    const float* __restrict__ z, const float* __restrict__ z_next,
    const float* __restrict__ b2,
    float* __restrict__ pw, unsigned* __restrict__ cnt, float* __restrict__ out)
{
    const int b = blockIdx.x;
    const int tid = threadIdx.x;
    const int w = tid >> 6, lane = tid & 63;
    __shared__ float gbuf[2][8][512];   // 32 KB double-buffered g chunks
    __shared__ float rn[104];           // raw neg dots, indexed by s-1
    __shared__ float sred[12];          // [0:4) max, [4:8) expsum, [8:12) count
    __shared__ float red[256];
    __shared__ int sdone;

    // long-lived regular loads (u/v for phase 1; sim row + diag for phase 2)
    float4 ua = *(const float4*)&u[b * 512 + lane * 4];
    float4 ub = *(const float4*)&u[b * 512 + 256 + lane * 4];
    float4 va = *(const float4*)&v[b * 512 + lane * 4];
    float4 vb = *(const float4*)&v[b * 512 + 256 + lane * 4];
    float4 s4 = *(const float4*)&sim[b * 1024 + tid * 4];
    float diag = sim[b * 1024 + b];

    const int r0 = w, r1 = w + 4;    // the 2 chunk-slots this wave stages+computes

    // ---- stage chunk 0 (4 async 16B ops per wave = 16KB/block-chunk) ----
    {
        int j0 = (b + 1 + r0) & (B_SZ - 1);
        int j1 = (b + 1 + r1) & (B_SZ - 1);
        gld_lds16(&g[j0 * 512 + lane * 4],       &gbuf[0][r0][0]);
        gld_lds16(&g[j0 * 512 + 256 + lane * 4], &gbuf[0][r0][256]);
        gld_lds16(&g[j1 * 512 + lane * 4],       &gbuf[0][r1][0]);
        gld_lds16(&g[j1 * 512 + 256 + lane * 4], &gbuf[0][r1][256]);
    }

    // ---- 13 chunks, double buffered; pad idx to 104 (rn writes guarded) ----
    for (int c = 0; c < 12; ++c) {
        const int bi = c & 1, bn = bi ^ 1;
        {   // prefetch chunk c+1 into the other buffer (stays in flight)
            int i0 = (c + 1) * 8 + r0, i1 = (c + 1) * 8 + r1;
            int j0 = (b + 1 + i0) & (B_SZ - 1);
            int j1 = (b + 1 + i1) & (B_SZ - 1);
            gld_lds16(&g[j0 * 512 + lane * 4],       &gbuf[bn][r0][0]);
            gld_lds16(&g[j0 * 512 + 256 + lane * 4], &gbuf[bn][r0][256]);
            gld_lds16(&g[j1 * 512 + lane * 4],       &gbuf[bn][r1][0]);
            gld_lds16(&g[j1 * 512 + 256 + lane * 4], &gbuf[bn][r1][256]);
        }
        VMWAIT(4);          // own chunk-c ops done; chunk-(c+1) 4 ops may remain
        raw_barrier();      // all waves' chunk-c ops done -> chunk c fully in LDS
        {   // consume chunk c: this wave's rows r0, r1
            float4 g0 = *(const float4*)&gbuf[bi][r0][lane * 4];
            float4 g1 = *(const float4*)&gbuf[bi][r0][256 + lane * 4];
            float4 h0 = *(const float4*)&gbuf[bi][r1][lane * 4];
            float4 h1 = *(const float4*)&gbuf[bi][r1][256 + lane * 4];
            float t0 = 0.0f, t1 = 0.0f;
            t0 += fmaxf(ua.x + g0.x, 0.0f) * va.x;  t1 += fmaxf(ua.x + h0.x, 0.0f) * va.x;
            t0 += fmaxf(ua.y + g0.y, 0.0f) * va.y;  t1 += fmaxf(ua.y + h0.y, 0.0f) * va.y;
            t0 += fmaxf(ua.z + g0.z, 0.0f) * va.z;  t1 += fmaxf(ua.z + h0.z, 0.0f) * va.z;
            t0 += fmaxf(ua.w + g0.w, 0.0f) * va.w;  t1 += fmaxf(ua.w + h0.w, 0.0f) * va.w;
            t0 += fmaxf(ub.x + g1.x, 0.0f) * vb.x;  t1 += fmaxf(ub.x + h1.x, 0.0f) * vb.x;
            t0 += fmaxf(ub.y + g1.y, 0.0f) * vb.y;  t1 += fmaxf(ub.y + h1.y, 0.0f) * vb.y;
            t0 += fmaxf(ub.z + g1.z, 0.0f) * vb.z;  t1 += fmaxf(ub.z + h1.z, 0.0f) * vb.z;
            t0 += fmaxf(ub.w + g1.w, 0.0f) * vb.w;  t1 += fmaxf(ub.w + h1.w, 0.0f) * vb.w;
            for (int off = 32; off; off >>= 1) {
                t0 += __shfl_down(t0, off);
                t1 += __shfl_down(t1, off);
            }
            if (lane == 0) {
                int i0 = c * 8 + r0, i1 = c * 8 + r1;
                if (i0 < NNEG) rn[i0] = t0;
                if (i1 < NNEG) rn[i1] = t1;
            }
        }
        raw_barrier();      // protect buffer bi before chunk c+2 restages it
    }
    VMWAIT(0);
    raw_barrier();
    {   // consume final chunk 12 (buffer 0); only idx<99 slots written
        const int bi = 0, c = 12;
        float4 g0 = *(const float4*)&gbuf[bi][r0][lane * 4];
        float4 g1 = *(const float4*)&gbuf[bi][r0][256 + lane * 4];
        float t0 = 0.0f;
        t0 += fmaxf(ua.x + g0.x, 0.0f) * va.x;
        t0 += fmaxf(ua.y + g0.y, 0.0f) * va.y;
        t0 += fmaxf(ua.z + g0.z, 0.0f) * va.z;
        t0 += fmaxf(ua.w + g0.w, 0.0f) * va.w;
        t0 += fmaxf(ub.x + g1.x, 0.0f) * vb.x;
        t0 += fmaxf(ub.y + g1.y, 0.0f) * vb.y;
        t0 += fmaxf(ub.z + g1.z, 0.0f) * vb.z;
        t0 += fmaxf(ub.w + g1.w, 0.0f) * vb.w;
        for (int off = 32; off; off >>= 1) t0 += __shfl_down(t0, off);
        if (lane == 0) {
            int i0 = c * 8 + r0;
            if (i0 < NNEG) rn[i0] = t0;
        }
    }

    // ---- c0 = (z[b]+b2) . z_next[b], after the pipeline (loads drain here) --
    float p;
    {
        float4 za = *(const float4*)&z[b * 512 + lane * 4];
        float4 zb = *(const float4*)&z[b * 512 + 256 + lane * 4];
        float4 na = *(const float4*)&z_next[b * 512 + lane * 4];
        float4 nb = *(const float4*)&z_next[b * 512 + 256 + lane * 4];
        float4 ca = *(const float4*)&b2[lane * 4];
        float4 cb = *(const float4*)&b2[256 + lane * 4];
        p  = (za.x + ca.x) * na.x + (za.y + ca.y) * na.y + (za.z + ca.z) * na.z + (za.w + ca.w) * na.w;
        p += (zb.x + cb.x) * nb.x + (zb.y + cb.y) * nb.y + (zb.z + cb.z) * nb.z + (zb.w + cb.w) * nb.w;
    }
    for (int off = 32; off; off >>= 1) p += __shfl_down(p, off);
    const float c0 = __shfl(p, 0);
    __syncthreads();   // rn complete & visible (safe: pipeline fully drained)

    // -------- phase 2: softmax + rank, 256 threads x 4 sim entries --------
    float neg = (tid < NNEG) ? (rn[tid] + c0) : -3.4e38f;

    float m = fmaxf(fmaxf(s4.x, s4.y), fmaxf(s4.z, s4.w));
    m = fmaxf(m, neg);
    for (int off = 32; off; off >>= 1) m = fmaxf(m, __shfl_xor(m, off));
    if (lane == 0) sred[w] = m;
    __syncthreads();
    m = fmaxf(fmaxf(sred[0], sred[1]), fmaxf(sred[2], sred[3]));

    float es = 0.0f; int ck = 0;
    {
        float xs[4] = {s4.x, s4.y, s4.z, s4.w};
#pragma unroll
        for (int c = 0; c < 4; ++c) {
            int j = tid * 4 + c;
            float x = xs[c];
            es += __expf((x - m) * INV_T);
            if (x > diag) ck++;
            else if (j < b && x == diag) ck++;   // tie-break: lower index wins
        }
    }
    if (tid < NNEG) {
        es += __expf((neg - m) * INV_T);
        if (neg > diag) ck++;
    }
    float ckf = (float)ck;
    for (int off = 32; off; off >>= 1) {
        es += __shfl_down(es, off);
        ckf += __shfl_down(ckf, off);
    }
    if (lane == 0) { sred[4 + w] = es; sred[8 + w] = ckf; }
    __syncthreads();
    if (tid == 0) {
        float est = sred[4] + sred[5] + sred[6] + sred[7];
        int ckt = (int)(sred[8] + sred[9] + sred[10] + sred[11]);
        pw[b * 4 + 0] = (m - diag) * INV_T + logf(est);
        pw[b * 4 + 1] = (ckt < 1) ? 1.0f : 0.0f;
        pw[b * 4 + 2] = (ckt < 3) ? 1.0f : 0.0f;
        pw[b * 4 + 3] = (ckt < 10) ? 1.0f : 0.0f;
        __threadfence();
        unsigned old = atomicAdd(cnt, 1u);
        sdone = (old == 1023u) ? 1 : 0;
    }
    __syncthreads();
    if (sdone) {
        __threadfence();
        int c = tid & 3;
        float s = 0.0f;
        for (int r = tid >> 2; r < 1024; r += 64) s += pw[r * 4 + c];
        red[tid] = s;
        __syncthreads();
        if (tid < 4) {
            float t = 0.0f;
            for (int q = 0; q < 64; ++q) t += red[tid + q * 4];
            out[tid] = t * (1.0f / (float)B_SZ);
        }
    }
}

// ---------------------------------------------------------------------------
extern "C" void kernel_launch(void* const* d_in, const int* in_sizes, int n_in,
                              void* d_out, int out_size, void* d_ws, size_t ws_size,
                              hipStream_t stream) {
    const float* z          = (const float*)d_in[0];
    const float* z_next     = (const float*)d_in[1];
    const float* z_next_hat = (const float*)d_in[2];
    const float* actions    = (const float*)d_in[3];
    const float* Wa         = (const float*)d_in[4];
    const float* ba         = (const float*)d_in[5];
    const float* W1         = (const float*)d_in[6];
    const float* b1         = (const float*)d_in[7];
    const float* W2         = (const float*)d_in[8];
    const float* b2         = (const float*)d_in[9];
    float* out = (float*)d_out;

    float* ws   = (float*)d_ws;
    float* sim  = ws;                          // 1024*1024
    float* u    = sim + B_SZ * B_SZ;           // 1024*512
    float* v    = u + B_SZ * ZH;               // 1024*512
    float* g    = v + B_SZ * ZH;               // 1024*512
    float* W1T  = g + B_SZ * ZH;               // 512*576
    float* ha   = W1T + 512 * 576;             // 1024*64
    float* pw   = ha + B_SZ * AH;              // 1024*4
    unsigned* cnt = (unsigned*)(pw + B_SZ * 4);

    prep_kernel<<<88, 256, 0, stream>>>(W1, actions, Wa, ba, W1T, ha, cnt);
    mm_kernel<<<640, 256, 0, stream>>>(z, z_next, z_next_hat, W1T, b1, W2, ha,
                                       sim, u, v, g);
    row2_kernel<<<1024, 256, 0, stream>>>(sim, u, v, g, z, z_next, b2, pw, cnt, out);
}

// Round 5
// 119.820 us; speedup vs baseline: 1.1386x; 1.1386x over previous
//
#include <hip/hip_runtime.h>
#include <math.h>

#define B_SZ 1024
#define Z_DIM 512
#define A_DIM 8
#define AH 64
#define ZH 512
#define NNEG 99
#define INV_T 10.0f

typedef __attribute__((ext_vector_type(8))) short short8;   // 8 bf16 (16 B)
typedef __attribute__((ext_vector_type(4))) float f32x4;

// fp32 -> bf16 round-to-nearest-even (unbiased; rel err <= 2^-9)
__device__ __forceinline__ short bf16rn(float x) {
    unsigned u = __float_as_uint(x);
    u += 0x7fffu + ((u >> 16) & 1u);
    return (short)(u >> 16);
}
__device__ __forceinline__ void cvt8rn(float4 x0, float4 x1, short8& h) {
    h[0] = bf16rn(x0.x); h[1] = bf16rn(x0.y); h[2] = bf16rn(x0.z); h[3] = bf16rn(x0.w);
    h[4] = bf16rn(x1.x); h[5] = bf16rn(x1.y); h[6] = bf16rn(x1.z); h[7] = bf16rn(x1.w);
}

// XOR-swizzled 16B-unit index into a [64 rows][8 units] bf16 tile (no padding).
__device__ __forceinline__ int sw(int m, int kb) { return m * 8 + (kb ^ (m & 7)); }

// ---------------------------------------------------------------------------
// prep: blocks [0,72) transpose W1 [576][512] -> W1T [512][576];
//       blocks [72,88) compute ha = relu(actions@Wa+ba)  [1024][64].
__global__ __launch_bounds__(256) void prep_kernel(
    const float* __restrict__ W1, const float* __restrict__ actions,
    const float* __restrict__ Wa, const float* __restrict__ ba,
    float* __restrict__ W1T, float* __restrict__ ha)
{
    const int id = blockIdx.x, tid = threadIdx.x;
    if (id < 72) {
        __shared__ float L[64][68];
        int kt = id >> 3, nt = id & 7;
#pragma unroll
        for (int i = 0; i < 4; ++i) {
            int f = tid + i * 256;
            int r = f >> 4, c4 = (f & 15) << 2;
            *(float4*)&L[r][c4] = *(const float4*)&W1[(kt * 64 + r) * 512 + nt * 64 + c4];
        }
        __syncthreads();
#pragma unroll
        for (int i = 0; i < 4; ++i) {
            int f = tid + i * 256;
            int r = f >> 4, c4 = (f & 15) << 2;
            float4 o = {L[c4][r], L[c4 + 1][r], L[c4 + 2][r], L[c4 + 3][r]};
            *(float4*)&W1T[(nt * 64 + r) * 576 + kt * 64 + c4] = o;
        }
    } else if (id < 88) {
        __shared__ float sWa[A_DIM * 64];
        __shared__ float sba[64];
        __shared__ float sact[64][A_DIM];
        int j0 = (id - 72) * 64;
        for (int i = tid; i < A_DIM * 64; i += 256) sWa[i] = Wa[i];
        if (tid < 64) sba[tid] = ba[tid];
        for (int i = tid; i < 64 * A_DIM; i += 256) (&sact[0][0])[i] = actions[j0 * A_DIM + i];
        __syncthreads();
        int r = tid >> 2, c0 = (tid & 3) * 16;
        float o[16];
#pragma unroll
        for (int c = 0; c < 16; ++c) o[c] = sba[c0 + c];
#pragma unroll
        for (int k = 0; k < A_DIM; ++k) {
            float a = sact[r][k];
#pragma unroll
            for (int c = 0; c < 16; ++c) o[c] += a * sWa[k * 64 + c0 + c];
        }
#pragma unroll
        for (int c = 0; c < 16; c += 4) {
            float4 v4 = {fmaxf(o[c], 0.f), fmaxf(o[c + 1], 0.f),
                         fmaxf(o[c + 2], 0.f), fmaxf(o[c + 3], 0.f)};
            *(float4*)&ha[(j0 + r) * 64 + c0 + c] = v4;
        }
    }
}

// ---------------------------------------------------------------------------
// Uniform NT MFMA GEMM, 640 blocks, plain bf16 (RN conversion at staging):
//   seg0 [  0,256): sim = z_next @ z_next_hat^T [1024x1024 K=512]
//   seg1 [256,384): u   = z @ W1T[:, :512]^T+b1 [1024x512  K=512]
//   seg2 [384,512): v   = z_next @ W2^T         [1024x512  K=512]
//   seg3 [512,640): g   = ha @ W1T[:,512:]^T    [1024x512  K=64]
__global__ __launch_bounds__(256) void mm_kernel(
    const float* __restrict__ z, const float* __restrict__ z_next,
    const float* __restrict__ z_next_hat, const float* __restrict__ W1T,
    const float* __restrict__ b1, const float* __restrict__ W2,
    const float* __restrict__ ha,
    float* __restrict__ sim, float* __restrict__ u, float* __restrict__ v,
    float* __restrict__ g)
{
    __shared__ short Ah[4096], Bh[4096];   // 16 KB

    const int id = blockIdx.x;
    const int tid = threadIdx.x;

    const float* Aop; const float* Bop; const float* bias = nullptr;
    float* C; int N, K, lda, ldb, bm0, bn0;
    if (id < 256) {
        int t = id; bn0 = (t & 15) * 64; bm0 = (t >> 4) * 64;
        Aop = z_next; lda = 512; Bop = z_next_hat; ldb = 512;
        C = sim; N = 1024; K = 512;
    } else if (id < 384) {
        int t = id - 256; bn0 = (t & 7) * 64; bm0 = (t >> 3) * 64;
        Aop = z; lda = 512; Bop = W1T; ldb = 576;
        C = u; N = 512; K = 512; bias = b1;
    } else if (id < 512) {
        int t = id - 384; bn0 = (t & 7) * 64; bm0 = (t >> 3) * 64;
        Aop = z_next; lda = 512; Bop = W2; ldb = 512;
        C = v; N = 512; K = 512;
    } else {
        int t = id - 512; bn0 = (t & 7) * 64; bm0 = (t >> 3) * 64;
        Aop = ha; lda = 64; Bop = W1T + 512; ldb = 576;
        C = g; N = 512; K = 64;
    }

    const int lane = tid & 63, wv = tid >> 6;
    const int lm = lane & 15, lq = lane >> 4;
    const int wm = (wv >> 1) * 32, wn = (wv & 1) * 32;
    const int sr = tid >> 2, sq = tid & 3;     // staging: row, 16-float quarter
    short8* Ah8 = (short8*)Ah; short8* Bh8 = (short8*)Bh;
    f32x4 acc[2][2] = {};

    for (int k0 = 0; k0 < K; k0 += 64) {
        {   // A: 16 consecutive floats of row sr -> units 2sq, 2sq+1
            const float* base = &Aop[(bm0 + sr) * lda + k0 + sq * 16];
            float4 x0 = *(const float4*)(base + 0), x1 = *(const float4*)(base + 4);
            float4 x2 = *(const float4*)(base + 8), x3 = *(const float4*)(base + 12);
            short8 h;
            cvt8rn(x0, x1, h); Ah8[sw(sr, 2 * sq)] = h;
            cvt8rn(x2, x3, h); Ah8[sw(sr, 2 * sq + 1)] = h;
        }
        {   // B: same, NT layout
            const float* base = &Bop[(bn0 + sr) * ldb + k0 + sq * 16];
            float4 x0 = *(const float4*)(base + 0), x1 = *(const float4*)(base + 4);
            float4 x2 = *(const float4*)(base + 8), x3 = *(const float4*)(base + 12);
            short8 h;
            cvt8rn(x0, x1, h); Bh8[sw(sr, 2 * sq)] = h;
            cvt8rn(x2, x3, h); Bh8[sw(sr, 2 * sq + 1)] = h;
        }
        __syncthreads();
#pragma unroll
        for (int kk = 0; kk < 64; kk += 32) {
            int kbi = (kk >> 3) + lq;
            short8 ah[2], bh[2];
#pragma unroll
            for (int i = 0; i < 2; ++i) {
                ah[i] = Ah8[sw(wm + i * 16 + lm, kbi)];
                bh[i] = Bh8[sw(wn + i * 16 + lm, kbi)];
            }
#pragma unroll
            for (int i = 0; i < 2; ++i)
#pragma unroll
                for (int j = 0; j < 2; ++j)
                    acc[i][j] = __builtin_amdgcn_mfma_f32_16x16x32_bf16(ah[i], bh[j], acc[i][j], 0, 0, 0);
        }
        __syncthreads();
    }
    // epilogue: C layout col=lane&15, row=(lane>>4)*4+reg
#pragma unroll
    for (int i = 0; i < 2; ++i)
#pragma unroll
        for (int j = 0; j < 2; ++j) {
            int n = bn0 + wn + j * 16 + lm;
            float bb = bias ? bias[n] : 0.0f;
#pragma unroll
            for (int r = 0; r < 4; ++r) {
                int m = bm0 + wm + i * 16 + lq * 4 + r;
                C[m * N + n] = acc[i][j][r] + bb;
            }
        }
}

// ---------------------------------------------------------------------------
// row2 v6: IDENTICAL compute pipeline to v5 (async global_load_lds, counted
// vmcnt, raw barriers), but the finalization protocol is GONE.  Evidence
// (R0/R1/R3/R4): four structurally different row2 loops all pinned at
// 43-50us, and cache-resident repeats (hbm_bytes=65KB) ALSO took 50us =>
// the invariant cost was the tail: per-block __threadfence (device-scope L2
// writeback) + same-address device-scope atomicAdd(cnt), serialized at the
// cross-XCD coherence point (~40ns x 1024 blocks ~ 41us; fits R0's 256-block
// 10us tail + slow loop, and R1/R4's 1024-block 41us tail + fast loop).
// Now each block just writes its 4 partials to pw and exits; a separate
// final_kernel launch does the 16KB reduction (stream order + kernel-boundary
// coherence replace the fence/atomic/sdone machinery).
#define VMWAIT(N) asm volatile("s_waitcnt vmcnt(" #N ")" ::: "memory")
__device__ __forceinline__ void raw_barrier() {
    asm volatile("" ::: "memory");
    __builtin_amdgcn_s_barrier();
    asm volatile("" ::: "memory");
}
typedef const __attribute__((address_space(1))) void* gas_ptr;
typedef __attribute__((address_space(3))) void* las_ptr;
__device__ __forceinline__ void gld_lds16(const float* gsrc, float* ldst) {
    __builtin_amdgcn_global_load_lds((gas_ptr)gsrc, (las_ptr)ldst, 16, 0, 0);
}

__global__ __launch_bounds__(256, 4) void row2_kernel(
    const float* __restrict__ sim, const float* __restrict__ u,
    const float* __restrict__ v, const float* __restrict__ g,
    const float* __restrict__ z, const float* __restrict__ z_next,
    const float* __restrict__ b2,
    float* __restrict__ pw)
{
    const int b = blockIdx.x;
    const int tid = threadIdx.x;
    const int w = tid >> 6, lane = tid & 63;
    __shared__ float gbuf[2][8][512];   // 32 KB double-buffered g chunks
    __shared__ float rn[104];           // raw neg dots, indexed by s-1
    __shared__ float sred[12];          // [0:4) max, [4:8) expsum, [8:12) count

    // long-lived regular loads (u/v for phase 1; sim row + diag for phase 2)
    float4 ua = *(const float4*)&u[b * 512 + lane * 4];
    float4 ub = *(const float4*)&u[b * 512 + 256 + lane * 4];
    float4 va = *(const float4*)&v[b * 512 + lane * 4];
    float4 vb = *(const float4*)&v[b * 512 + 256 + lane * 4];
    float4 s4 = *(const float4*)&sim[b * 1024 + tid * 4];
    float diag = sim[b * 1024 + b];

    const int r0 = w, r1 = w + 4;    // the 2 chunk-slots this wave stages+computes

    // ---- stage chunk 0 (4 async 16B ops per wave = 16KB/block-chunk) ----
    {
        int j0 = (b + 1 + r0) & (B_SZ - 1);
        int j1 = (b + 1 + r1) & (B_SZ - 1);
        gld_lds16(&g[j0 * 512 + lane * 4],       &gbuf[0][r0][0]);
        gld_lds16(&g[j0 * 512 + 256 + lane * 4], &gbuf[0][r0][256]);
        gld_lds16(&g[j1 * 512 + lane * 4],       &gbuf[0][r1][0]);
        gld_lds16(&g[j1 * 512 + 256 + lane * 4], &gbuf[0][r1][256]);
    }

    // ---- 13 chunks, double buffered; pad idx to 104 (rn writes guarded) ----
    for (int c = 0; c < 12; ++c) {
        const int bi = c & 1, bn = bi ^ 1;
        {   // prefetch chunk c+1 into the other buffer (stays in flight)
            int i0 = (c + 1) * 8 + r0, i1 = (c + 1) * 8 + r1;
            int j0 = (b + 1 + i0) & (B_SZ - 1);
            int j1 = (b + 1 + i1) & (B_SZ - 1);
            gld_lds16(&g[j0 * 512 + lane * 4],       &gbuf[bn][r0][0]);
            gld_lds16(&g[j0 * 512 + 256 + lane * 4], &gbuf[bn][r0][256]);
            gld_lds16(&g[j1 * 512 + lane * 4],       &gbuf[bn][r1][0]);
            gld_lds16(&g[j1 * 512 + 256 + lane * 4], &gbuf[bn][r1][256]);
        }
        VMWAIT(4);          // own chunk-c ops done; chunk-(c+1) 4 ops may remain
        raw_barrier();      // all waves' chunk-c ops done -> chunk c fully in LDS
        {   // consume chunk c: this wave's rows r0, r1
            float4 g0 = *(const float4*)&gbuf[bi][r0][lane * 4];
            float4 g1 = *(const float4*)&gbuf[bi][r0][256 + lane * 4];
            float4 h0 = *(const float4*)&gbuf[bi][r1][lane * 4];
            float4 h1 = *(const float4*)&gbuf[bi][r1][256 + lane * 4];
            float t0 = 0.0f, t1 = 0.0f;
            t0 += fmaxf(ua.x + g0.x, 0.0f) * va.x;  t1 += fmaxf(ua.x + h0.x, 0.0f) * va.x;
            t0 += fmaxf(ua.y + g0.y, 0.0f) * va.y;  t1 += fmaxf(ua.y + h0.y, 0.0f) * va.y;
            t0 += fmaxf(ua.z + g0.z, 0.0f) * va.z;  t1 += fmaxf(ua.z + h0.z, 0.0f) * va.z;
            t0 += fmaxf(ua.w + g0.w, 0.0f) * va.w;  t1 += fmaxf(ua.w + h0.w, 0.0f) * va.w;
            t0 += fmaxf(ub.x + g1.x, 0.0f) * vb.x;  t1 += fmaxf(ub.x + h1.x, 0.0f) * vb.x;
            t0 += fmaxf(ub.y + g1.y, 0.0f) * vb.y;  t1 += fmaxf(ub.y + h1.y, 0.0f) * vb.y;
            t0 += fmaxf(ub.z + g1.z, 0.0f) * vb.z;  t1 += fmaxf(ub.z + h1.z, 0.0f) * vb.z;
            t0 += fmaxf(ub.w + g1.w, 0.0f) * vb.w;  t1 += fmaxf(ub.w + h1.w, 0.0f) * vb.w;
            for (int off = 32; off; off >>= 1) {
                t0 += __shfl_down(t0, off);
                t1 += __shfl_down(t1, off);
            }
            if (lane == 0) {
                int i0 = c * 8 + r0, i1 = c * 8 + r1;
                if (i0 < NNEG) rn[i0] = t0;
                if (i1 < NNEG) rn[i1] = t1;
            }
        }
        raw_barrier();      // protect buffer bi before chunk c+2 restages it
    }
    VMWAIT(0);
    raw_barrier();
    {   // consume final chunk 12 (buffer 0); only idx<99 slots written
        const int bi = 0, c = 12;
        float4 g0 = *(const float4*)&gbuf[bi][r0][lane * 4];
        float4 g1 = *(const float4*)&gbuf[bi][r0][256 + lane * 4];
        float t0 = 0.0f;
        t0 += fmaxf(ua.x + g0.x, 0.0f) * va.x;
        t0 += fmaxf(ua.y + g0.y, 0.0f) * va.y;
        t0 += fmaxf(ua.z + g0.z, 0.0f) * va.z;
        t0 += fmaxf(ua.w + g0.w, 0.0f) * va.w;
        t0 += fmaxf(ub.x + g1.x, 0.0f) * vb.x;
        t0 += fmaxf(ub.y + g1.y, 0.0f) * vb.y;
        t0 += fmaxf(ub.z + g1.z, 0.0f) * vb.z;
        t0 += fmaxf(ub.w + g1.w, 0.0f) * vb.w;
        for (int off = 32; off; off >>= 1) t0 += __shfl_down(t0, off);
        if (lane == 0) {
            int i0 = c * 8 + r0;
            if (i0 < NNEG) rn[i0] = t0;
        }
    }

    // ---- c0 = (z[b]+b2) . z_next[b], after the pipeline (loads drain here) --
    float p;
    {
        float4 za = *(const float4*)&z[b * 512 + lane * 4];
        float4 zb = *(const float4*)&z[b * 512 + 256 + lane * 4];
        float4 na = *(const float4*)&z_next[b * 512 + lane * 4];
        float4 nb = *(const float4*)&z_next[b * 512 + 256 + lane * 4];
        float4 ca = *(const float4*)&b2[lane * 4];
        float4 cb = *(const float4*)&b2[256 + lane * 4];
        p  = (za.x + ca.x) * na.x + (za.y + ca.y) * na.y + (za.z + ca.z) * na.z + (za.w + ca.w) * na.w;
        p += (zb.x + cb.x) * nb.x + (zb.y + cb.y) * nb.y + (zb.z + cb.z) * nb.z + (zb.w + cb.w) * nb.w;
    }
    for (int off = 32; off; off >>= 1) p += __shfl_down(p, off);
    const float c0 = __shfl(p, 0);
    __syncthreads();   // rn complete & visible (safe: pipeline fully drained)

    // -------- phase 2: softmax + rank, 256 threads x 4 sim entries --------
    float neg = (tid < NNEG) ? (rn[tid] + c0) : -3.4e38f;

    float m = fmaxf(fmaxf(s4.x, s4.y), fmaxf(s4.z, s4.w));
    m = fmaxf(m, neg);
    for (int off = 32; off; off >>= 1) m = fmaxf(m, __shfl_xor(m, off));
    if (lane == 0) sred[w] = m;
    __syncthreads();
    m = fmaxf(fmaxf(sred[0], sred[1]), fmaxf(sred[2], sred[3]));

    float es = 0.0f; int ck = 0;
    {
        float xs[4] = {s4.x, s4.y, s4.z, s4.w};
#pragma unroll
        for (int c = 0; c < 4; ++c) {
            int j = tid * 4 + c;
            float x = xs[c];
            es += __expf((x - m) * INV_T);
            if (x > diag) ck++;
            else if (j < b && x == diag) ck++;   // tie-break: lower index wins
        }
    }
    if (tid < NNEG) {
        es += __expf((neg - m) * INV_T);
        if (neg > diag) ck++;
    }
    float ckf = (float)ck;
    for (int off = 32; off; off >>= 1) {
        es += __shfl_down(es, off);
        ckf += __shfl_down(ckf, off);
    }
    if (lane == 0) { sred[4 + w] = es; sred[8 + w] = ckf; }
    __syncthreads();
    if (tid == 0) {
        float est = sred[4] + sred[5] + sred[6] + sred[7];
        int ckt = (int)(sred[8] + sred[9] + sred[10] + sred[11]);
        pw[b * 4 + 0] = (m - diag) * INV_T + logf(est);
        pw[b * 4 + 1] = (ckt < 1) ? 1.0f : 0.0f;
        pw[b * 4 + 2] = (ckt < 3) ? 1.0f : 0.0f;
        pw[b * 4 + 3] = (ckt < 10) ? 1.0f : 0.0f;
    }
}

// ---------------------------------------------------------------------------
// final: 1 block x 256 threads, reduce pw[1024][4] -> out[4].
// Stream order guarantees row2 completion; kernel-boundary coherence makes
// pw visible without fences/atomics.
__global__ __launch_bounds__(256) void final_kernel(
    const float* __restrict__ pw, float* __restrict__ out)
{
    __shared__ float red[256];
    const int tid = threadIdx.x;
    const int c = tid & 3;
    float s = 0.0f;
    for (int r = tid >> 2; r < 1024; r += 64) s += pw[r * 4 + c];
    red[tid] = s;
    __syncthreads();
    if (tid < 4) {
        float t = 0.0f;
        for (int q = 0; q < 64; ++q) t += red[tid + q * 4];
        out[tid] = t * (1.0f / (float)B_SZ);
    }
}

// ---------------------------------------------------------------------------
extern "C" void kernel_launch(void* const* d_in, const int* in_sizes, int n_in,
                              void* d_out, int out_size, void* d_ws, size_t ws_size,
                              hipStream_t stream) {
    const float* z          = (const float*)d_in[0];
    const float* z_next     = (const float*)d_in[1];
    const float* z_next_hat = (const float*)d_in[2];
    const float* actions    = (const float*)d_in[3];
    const float* Wa         = (const float*)d_in[4];
    const float* ba         = (const float*)d_in[5];
    const float* W1         = (const float*)d_in[6];
    const float* b1         = (const float*)d_in[7];
    const float* W2         = (const float*)d_in[8];
    const float* b2         = (const float*)d_in[9];
    float* out = (float*)d_out;

    float* ws   = (float*)d_ws;
    float* sim  = ws;                          // 1024*1024
    float* u    = sim + B_SZ * B_SZ;           // 1024*512
    float* v    = u + B_SZ * ZH;               // 1024*512
    float* g    = v + B_SZ * ZH;               // 1024*512
    float* W1T  = g + B_SZ * ZH;               // 512*576
    float* ha   = W1T + 512 * 576;             // 1024*64
    float* pw   = ha + B_SZ * AH;              // 1024*4

    prep_kernel<<<88, 256, 0, stream>>>(W1, actions, Wa, ba, W1T, ha);
    mm_kernel<<<640, 256, 0, stream>>>(z, z_next, z_next_hat, W1T, b1, W2, ha,
                                       sim, u, v, g);
    row2_kernel<<<1024, 256, 0, stream>>>(sim, u, v, g, z, z_next, b2, pw);
    final_kernel<<<1, 256, 0, stream>>>(pw, out);
}

// Round 6
// 118.941 us; speedup vs baseline: 1.1470x; 1.0074x over previous
//
#include <hip/hip_runtime.h>
#include <math.h>

#define B_SZ 1024
#define Z_DIM 512
#define A_DIM 8
#define AH 64
#define ZH 512
#define NNEG 99
#define INV_T 10.0f

typedef __attribute__((ext_vector_type(8))) short short8;   // 8 bf16 (16 B)
typedef __attribute__((ext_vector_type(4))) float f32x4;

// fp32 -> bf16 round-to-nearest-even (unbiased; rel err <= 2^-9)
__device__ __forceinline__ short bf16rn(float x) {
    unsigned u = __float_as_uint(x);
    u += 0x7fffu + ((u >> 16) & 1u);
    return (short)(u >> 16);
}
__device__ __forceinline__ void cvt8rn(float4 x0, float4 x1, short8& h) {
    h[0] = bf16rn(x0.x); h[1] = bf16rn(x0.y); h[2] = bf16rn(x0.z); h[3] = bf16rn(x0.w);
    h[4] = bf16rn(x1.x); h[5] = bf16rn(x1.y); h[6] = bf16rn(x1.z); h[7] = bf16rn(x1.w);
}

// XOR-swizzled 16B-unit index into a [64 rows][8 units] bf16 tile (no padding).
__device__ __forceinline__ int sw(int m, int kb) { return m * 8 + (kb ^ (m & 7)); }

#define VMWAIT(N) asm volatile("s_waitcnt vmcnt(" #N ")" ::: "memory")
__device__ __forceinline__ void raw_barrier() {
    asm volatile("" ::: "memory");
    __builtin_amdgcn_s_barrier();
    asm volatile("" ::: "memory");
}
typedef const __attribute__((address_space(1))) void* gas_ptr;
typedef __attribute__((address_space(3))) void* las_ptr;
__device__ __forceinline__ void gld_lds16(const float* gsrc, float* ldst) {
    __builtin_amdgcn_global_load_lds((gas_ptr)gsrc, (las_ptr)ldst, 16, 0, 0);
}

// ---------------------------------------------------------------------------
// mm v7: prep fused away.  Uniform NT MFMA GEMM, 640 blocks:
//   seg0 [  0,256): sim = z_next @ z_next_hat^T [1024x1024 K=512]  mode 0
//   seg1 [256,384): u   = z @ W1[:512]  + b1    [1024x512  K=512]  mode 1
//   seg2 [384,512): v   = z_next @ W2^T         [1024x512  K=512]  mode 0
//   seg3 [512,640): g   = relu(act@Wa+ba) @ W1[512:]  [1024x512 K=64] mode 2
// mode 0: B rows are [N][K] (NT, direct).  mode 1/2: B = W1 rows k, cols n —
// staged via scalar-scatter bf16 transpose (LDS image identical to the old
// W1T path).  mode 2 additionally computes its A-operand (ha tile) in-block:
// 64x64x8 matmul + relu, written straight into the Ah fragment slots.
__global__ __launch_bounds__(256) void mm_kernel(
    const float* __restrict__ z, const float* __restrict__ z_next,
    const float* __restrict__ z_next_hat, const float* __restrict__ W1,
    const float* __restrict__ b1, const float* __restrict__ W2,
    const float* __restrict__ actions, const float* __restrict__ Wa,
    const float* __restrict__ ba,
    float* __restrict__ sim, float* __restrict__ u, float* __restrict__ v,
    float* __restrict__ g)
{
    __shared__ short Ah[4096], Bh[4096];   // 16 KB
    __shared__ float sWa[A_DIM * 64];
    __shared__ float sba[64];

    const int id = blockIdx.x;
    const int tid = threadIdx.x;

    const float* Aop = nullptr; const float* Bsrc; const float* bias = nullptr;
    float* C; int N, K, bm0, bn0, mode;
    if (id < 256) {
        int t = id; bn0 = (t & 15) * 64; bm0 = (t >> 4) * 64;
        Aop = z_next; Bsrc = z_next_hat; C = sim; N = 1024; K = 512; mode = 0;
    } else if (id < 384) {
        int t = id - 256; bn0 = (t & 7) * 64; bm0 = (t >> 3) * 64;
        Aop = z; Bsrc = W1; C = u; N = 512; K = 512; bias = b1; mode = 1;
    } else if (id < 512) {
        int t = id - 384; bn0 = (t & 7) * 64; bm0 = (t >> 3) * 64;
        Aop = z_next; Bsrc = W2; C = v; N = 512; K = 512; mode = 0;
    } else {
        int t = id - 512; bn0 = (t & 7) * 64; bm0 = (t >> 3) * 64;
        Bsrc = W1 + 512 * 512; C = g; N = 512; K = 64; mode = 2;
    }

    const int lane = tid & 63, wv = tid >> 6;
    const int lm = lane & 15, lq = lane >> 4;
    const int wm = (wv >> 1) * 32, wn = (wv & 1) * 32;
    const int sr = tid >> 2, sq = tid & 3;     // staging: row, 16-float quarter
    short8* Ah8 = (short8*)Ah; short8* Bh8 = (short8*)Bh;
    f32x4 acc[2][2] = {};

    // mode 2: compute this block's ha tile (A operand) into registers.
    float aA[16];
    if (mode == 2) {
        for (int i = tid; i < A_DIM * 64; i += 256) sWa[i] = Wa[i];
        if (tid < 64) sba[tid] = ba[tid];
        __syncthreads();
        float4 a0 = *(const float4*)&actions[(bm0 + sr) * A_DIM + 0];
        float4 a1 = *(const float4*)&actions[(bm0 + sr) * A_DIM + 4];
        float av[8] = {a0.x, a0.y, a0.z, a0.w, a1.x, a1.y, a1.z, a1.w};
#pragma unroll
        for (int c = 0; c < 16; ++c) aA[c] = sba[sq * 16 + c];
#pragma unroll
        for (int k = 0; k < A_DIM; ++k)
#pragma unroll
            for (int c = 0; c < 16; ++c) aA[c] += av[k] * sWa[k * 64 + sq * 16 + c];
#pragma unroll
        for (int c = 0; c < 16; ++c) aA[c] = fmaxf(aA[c], 0.0f);
    }

    for (int k0 = 0; k0 < K; k0 += 64) {
        if (mode != 2) {   // A: 16 consecutive floats of row sr -> units 2sq, 2sq+1
            const float* base = &Aop[(bm0 + sr) * 512 + k0 + sq * 16];
            float4 x0 = *(const float4*)(base + 0), x1 = *(const float4*)(base + 4);
            float4 x2 = *(const float4*)(base + 8), x3 = *(const float4*)(base + 12);
            short8 h;
            cvt8rn(x0, x1, h); Ah8[sw(sr, 2 * sq)] = h;
            cvt8rn(x2, x3, h); Ah8[sw(sr, 2 * sq + 1)] = h;
        } else {           // A from computed ha tile (same fragment slots)
            short8 h;
#pragma unroll
            for (int c = 0; c < 8; ++c) h[c] = bf16rn(aA[c]);
            Ah8[sw(sr, 2 * sq)] = h;
#pragma unroll
            for (int c = 0; c < 8; ++c) h[c] = bf16rn(aA[8 + c]);
            Ah8[sw(sr, 2 * sq + 1)] = h;
        }
        if (mode == 0) {   // B: NT direct
            const float* base = &Bsrc[(bn0 + sr) * 512 + k0 + sq * 16];
            float4 x0 = *(const float4*)(base + 0), x1 = *(const float4*)(base + 4);
            float4 x2 = *(const float4*)(base + 8), x3 = *(const float4*)(base + 12);
            short8 h;
            cvt8rn(x0, x1, h); Bh8[sw(sr, 2 * sq)] = h;
            cvt8rn(x2, x3, h); Bh8[sw(sr, 2 * sq + 1)] = h;
        } else {           // B: transpose of W1 rows (k0+sr), cols bn0+sq*16..
            const float* base = &Bsrc[(k0 + sr) * 512 + bn0 + sq * 16];
            float4 x0 = *(const float4*)(base + 0), x1 = *(const float4*)(base + 4);
            float4 x2 = *(const float4*)(base + 8), x3 = *(const float4*)(base + 12);
            float xs[16] = {x0.x, x0.y, x0.z, x0.w, x1.x, x1.y, x1.z, x1.w,
                            x2.x, x2.y, x2.z, x2.w, x3.x, x3.y, x3.z, x3.w};
            short* Bs = (short*)Bh;
            int kb = sr >> 3, ke = sr & 7;
#pragma unroll
            for (int t = 0; t < 16; ++t)
                Bs[sw(sq * 16 + t, kb) * 8 + ke] = bf16rn(xs[t]);
        }
        __syncthreads();
#pragma unroll
        for (int kk = 0; kk < 64; kk += 32) {
            int kbi = (kk >> 3) + lq;
            short8 ah[2], bh[2];
#pragma unroll
            for (int i = 0; i < 2; ++i) {
                ah[i] = Ah8[sw(wm + i * 16 + lm, kbi)];
                bh[i] = Bh8[sw(wn + i * 16 + lm, kbi)];
            }
#pragma unroll
            for (int i = 0; i < 2; ++i)
#pragma unroll
                for (int j = 0; j < 2; ++j)
                    acc[i][j] = __builtin_amdgcn_mfma_f32_16x16x32_bf16(ah[i], bh[j], acc[i][j], 0, 0, 0);
        }
        __syncthreads();
    }
    // epilogue: C layout col=lane&15, row=(lane>>4)*4+reg
#pragma unroll
    for (int i = 0; i < 2; ++i)
#pragma unroll
        for (int j = 0; j < 2; ++j) {
            int n = bn0 + wn + j * 16 + lm;
            float bb = bias ? bias[n] : 0.0f;
#pragma unroll
            for (int r = 0; r < 4; ++r) {
                int m = bm0 + wm + i * 16 + lq * 4 + r;
                C[m * N + n] = acc[i][j][r] + bb;
            }
        }
}

// ---------------------------------------------------------------------------
// row2 v7: 256 blocks x 256 threads, FOUR rows per block (wave w owns row
// b=blk*4+w).  Staged g-chunks (8 rows, 16 KB, async global_load_lds +
// counted vmcnt + raw barriers — v6's validated pipeline) are SHARED by all
// 4 waves: g L2 traffic drops 4x (218 -> 55 MB).  No atomic tail (R4->R5
// evidence: removing it was the first real win); partials go to pw, reduced
// by final_kernel.
__global__ __launch_bounds__(256) void row2_kernel(
    const float* __restrict__ sim, const float* __restrict__ u,
    const float* __restrict__ v, const float* __restrict__ g,
    const float* __restrict__ z, const float* __restrict__ z_next,
    const float* __restrict__ b2,
    float* __restrict__ pw)
{
    const int blk = blockIdx.x;
    const int tid = threadIdx.x;
    const int w = tid >> 6, lane = tid & 63;
    const int b = blk * 4 + w;
    __shared__ float gbuf[2][8][512];   // 32 KB double-buffered g chunks
    __shared__ float rn[4][100];        // c0 + neg dot, [wave][s-1]

    const int J0 = blk * 4;             // j = J0 + 1 + idx, idx in [0,104)

    // wave w stages rows 2w, 2w+1 of each chunk (4 x 16B-per-lane async ops)
    auto STAGE = [&](int c, int bi) {
        int i0 = c * 8 + 2 * w, i1 = i0 + 1;
        int j0 = (J0 + 1 + i0) & (B_SZ - 1);
        int j1 = (J0 + 1 + i1) & (B_SZ - 1);
        gld_lds16(&g[j0 * 512 + lane * 4],       &gbuf[bi][2 * w][0]);
        gld_lds16(&g[j0 * 512 + 256 + lane * 4], &gbuf[bi][2 * w][256]);
        gld_lds16(&g[j1 * 512 + lane * 4],       &gbuf[bi][2 * w + 1][0]);
        gld_lds16(&g[j1 * 512 + 256 + lane * 4], &gbuf[bi][2 * w + 1][256]);
    };
    STAGE(0, 0);   // issue before the register loads: overlaps their latency

    // long-lived loads: u/v row b (phase 1), sim row b + diag (phase 2)
    float4 ua = *(const float4*)&u[b * 512 + lane * 4];
    float4 ub = *(const float4*)&u[b * 512 + 256 + lane * 4];
    float4 va = *(const float4*)&v[b * 512 + lane * 4];
    float4 vb = *(const float4*)&v[b * 512 + 256 + lane * 4];
    float4 sv[4];
#pragma unroll
    for (int i = 0; i < 4; ++i)
        sv[i] = *(const float4*)&sim[b * 1024 + lane * 16 + i * 4];
    float diag = sim[b * 1024 + b];

    // c0 = (z[b]+b2) . z_next[b]  (per-wave)
    float p;
    {
        float4 za = *(const float4*)&z[b * 512 + lane * 4];
        float4 zb = *(const float4*)&z[b * 512 + 256 + lane * 4];
        float4 na = *(const float4*)&z_next[b * 512 + lane * 4];
        float4 nb = *(const float4*)&z_next[b * 512 + 256 + lane * 4];
        float4 ca = *(const float4*)&b2[lane * 4];
        float4 cb = *(const float4*)&b2[256 + lane * 4];
        p  = (za.x + ca.x) * na.x + (za.y + ca.y) * na.y + (za.z + ca.z) * na.z + (za.w + ca.w) * na.w;
        p += (zb.x + cb.x) * nb.x + (zb.y + cb.y) * nb.y + (zb.z + cb.z) * nb.z + (zb.w + cb.w) * nb.w;
    }
    for (int off = 32; off; off >>= 1) p += __shfl_down(p, off);
    const float c0 = __shfl(p, 0);

    // ---- 13 chunks of 8 rows, double-buffered async pipeline ----
    for (int c = 0; c < 12; ++c) {
        const int bi = c & 1, bn2 = bi ^ 1;
        STAGE(c + 1, bn2);          // prefetch stays in flight across barrier
        VMWAIT(4);                  // own chunk-c ops done (4 newest = c+1 remain)
        raw_barrier();              // all waves' chunk-c ops done
        float d[8];
#pragma unroll
        for (int ri = 0; ri < 8; ++ri) {
            float4 g0 = *(const float4*)&gbuf[bi][ri][lane * 4];
            float4 g1 = *(const float4*)&gbuf[bi][ri][256 + lane * 4];
            float t = 0.0f;
            t += fmaxf(ua.x + g0.x, 0.0f) * va.x;
            t += fmaxf(ua.y + g0.y, 0.0f) * va.y;
            t += fmaxf(ua.z + g0.z, 0.0f) * va.z;
            t += fmaxf(ua.w + g0.w, 0.0f) * va.w;
            t += fmaxf(ub.x + g1.x, 0.0f) * vb.x;
            t += fmaxf(ub.y + g1.y, 0.0f) * vb.y;
            t += fmaxf(ub.z + g1.z, 0.0f) * vb.z;
            t += fmaxf(ub.w + g1.w, 0.0f) * vb.w;
            d[ri] = t;
        }
        for (int off = 32; off; off >>= 1) {
#pragma unroll
            for (int ri = 0; ri < 8; ++ri) d[ri] += __shfl_down(d[ri], off);
        }
        if (lane == 0) {
#pragma unroll
            for (int ri = 0; ri < 8; ++ri) {
                int s1 = c * 8 + ri - w;           // s-1 for this wave's row
                if (s1 >= 0 && s1 < NNEG) rn[w][s1] = c0 + d[ri];
            }
        }
        raw_barrier();              // protect buffer bi before restaging
    }
    VMWAIT(0);
    raw_barrier();
    {   // final chunk 12 (buffer 0): idx 96..103, only s1<99 kept
        float d[8];
#pragma unroll
        for (int ri = 0; ri < 8; ++ri) {
            float4 g0 = *(const float4*)&gbuf[0][ri][lane * 4];
            float4 g1 = *(const float4*)&gbuf[0][ri][256 + lane * 4];
            float t = 0.0f;
            t += fmaxf(ua.x + g0.x, 0.0f) * va.x;
            t += fmaxf(ua.y + g0.y, 0.0f) * va.y;
            t += fmaxf(ua.z + g0.z, 0.0f) * va.z;
            t += fmaxf(ua.w + g0.w, 0.0f) * va.w;
            t += fmaxf(ub.x + g1.x, 0.0f) * vb.x;
            t += fmaxf(ub.y + g1.y, 0.0f) * vb.y;
            t += fmaxf(ub.z + g1.z, 0.0f) * vb.z;
            t += fmaxf(ub.w + g1.w, 0.0f) * vb.w;
            d[ri] = t;
        }
        for (int off = 32; off; off >>= 1) {
#pragma unroll
            for (int ri = 0; ri < 8; ++ri) d[ri] += __shfl_down(d[ri], off);
        }
        if (lane == 0) {
#pragma unroll
            for (int ri = 0; ri < 8; ++ri) {
                int s1 = 96 + ri - w;
                if (s1 >= 0 && s1 < NNEG) rn[w][s1] = c0 + d[ri];
            }
        }
    }
    __syncthreads();

    // -------- phase 2: per-wave softmax + rank on row b --------
    float nva = rn[w][lane];                                  // s-1 = 0..63
    float nvb = (lane < 35) ? rn[w][lane + 64] : -3.4e38f;    // s-1 = 64..98

    float m = fmaxf(nva, nvb);
#pragma unroll
    for (int i = 0; i < 4; ++i)
        m = fmaxf(m, fmaxf(fmaxf(sv[i].x, sv[i].y), fmaxf(sv[i].z, sv[i].w)));
    for (int off = 32; off; off >>= 1) m = fmaxf(m, __shfl_xor(m, off));

    float es = 0.0f; int ck = 0;
#pragma unroll
    for (int i = 0; i < 4; ++i) {
        float xs[4] = {sv[i].x, sv[i].y, sv[i].z, sv[i].w};
#pragma unroll
        for (int c = 0; c < 4; ++c) {
            int j = lane * 16 + i * 4 + c;
            float x = xs[c];
            es += __expf((x - m) * INV_T);
            if (x > diag) ck++;
            else if (j < b && x == diag) ck++;   // tie-break: lower index wins
        }
    }
    es += __expf((nva - m) * INV_T);
    if (nva > diag) ck++;
    if (lane < 35) {
        es += __expf((nvb - m) * INV_T);
        if (nvb > diag) ck++;
    }
    for (int off = 32; off; off >>= 1) {
        es += __shfl_down(es, off);
        ck += __shfl_down(ck, off);
    }
    if (lane == 0) {
        pw[b * 4 + 0] = (m - diag) * INV_T + logf(es);
        pw[b * 4 + 1] = (ck < 1) ? 1.0f : 0.0f;
        pw[b * 4 + 2] = (ck < 3) ? 1.0f : 0.0f;
        pw[b * 4 + 3] = (ck < 10) ? 1.0f : 0.0f;
    }
}

// ---------------------------------------------------------------------------
// final: 1 block x 256 threads, reduce pw[1024][4] -> out[4].
__global__ __launch_bounds__(256) void final_kernel(
    const float* __restrict__ pw, float* __restrict__ out)
{
    __shared__ float red[256];
    const int tid = threadIdx.x;
    const int c = tid & 3;
    float s = 0.0f;
    for (int r = tid >> 2; r < 1024; r += 64) s += pw[r * 4 + c];
    red[tid] = s;
    __syncthreads();
    if (tid < 4) {
        float t = 0.0f;
        for (int q = 0; q < 64; ++q) t += red[tid + q * 4];
        out[tid] = t * (1.0f / (float)B_SZ);
    }
}

// ---------------------------------------------------------------------------
extern "C" void kernel_launch(void* const* d_in, const int* in_sizes, int n_in,
                              void* d_out, int out_size, void* d_ws, size_t ws_size,
                              hipStream_t stream) {
    const float* z          = (const float*)d_in[0];
    const float* z_next     = (const float*)d_in[1];
    const float* z_next_hat = (const float*)d_in[2];
    const float* actions    = (const float*)d_in[3];
    const float* Wa         = (const float*)d_in[4];
    const float* ba         = (const float*)d_in[5];
    const float* W1         = (const float*)d_in[6];
    const float* b1         = (const float*)d_in[7];
    const float* W2         = (const float*)d_in[8];
    const float* b2         = (const float*)d_in[9];
    float* out = (float*)d_out;

    float* ws   = (float*)d_ws;
    float* sim  = ws;                          // 1024*1024
    float* u    = sim + B_SZ * B_SZ;           // 1024*512
    float* v    = u + B_SZ * ZH;               // 1024*512
    float* g    = v + B_SZ * ZH;               // 1024*512
    float* pw   = g + B_SZ * ZH;               // 1024*4

    mm_kernel<<<640, 256, 0, stream>>>(z, z_next, z_next_hat, W1, b1, W2,
                                       actions, Wa, ba, sim, u, v, g);
    row2_kernel<<<256, 256, 0, stream>>>(sim, u, v, g, z, z_next, b2, pw);
    final_kernel<<<1, 256, 0, stream>>>(pw, out);
}

// Round 7
// 115.233 us; speedup vs baseline: 1.1839x; 1.0322x over previous
//
#include <hip/hip_runtime.h>
#include <math.h>

#define B_SZ 1024
#define Z_DIM 512
#define A_DIM 8
#define AH 64
#define ZH 512
#define NNEG 99
#define INV_T 10.0f

typedef __attribute__((ext_vector_type(8))) short short8;   // 8 bf16 (16 B)
typedef __attribute__((ext_vector_type(4))) short short4b;  // 4 bf16 (8 B)
typedef __attribute__((ext_vector_type(4))) float f32x4;

// fp32 -> bf16 round-to-nearest-even (unbiased; rel err <= 2^-9)
__device__ __forceinline__ short bf16rn(float x) {
    unsigned u = __float_as_uint(x);
    u += 0x7fffu + ((u >> 16) & 1u);
    return (short)(u >> 16);
}
__device__ __forceinline__ void cvt8rn(float4 x0, float4 x1, short8& h) {
    h[0] = bf16rn(x0.x); h[1] = bf16rn(x0.y); h[2] = bf16rn(x0.z); h[3] = bf16rn(x0.w);
    h[4] = bf16rn(x1.x); h[5] = bf16rn(x1.y); h[6] = bf16rn(x1.z); h[7] = bf16rn(x1.w);
}

// XOR-swizzled 16B-unit index into a [rows][8 units] bf16 tile (no padding).
__device__ __forceinline__ int sw(int m, int kb) { return m * 8 + (kb ^ (m & 7)); }

#define VMWAIT(N) asm volatile("s_waitcnt vmcnt(" #N ")" ::: "memory")
__device__ __forceinline__ void raw_barrier() {
    asm volatile("" ::: "memory");
    __builtin_amdgcn_s_barrier();
    asm volatile("" ::: "memory");
}
typedef const __attribute__((address_space(1))) void* gas_ptr;
typedef __attribute__((address_space(3))) void* las_ptr;
__device__ __forceinline__ void gld_lds16(const void* gsrc, void* ldst) {
    __builtin_amdgcn_global_load_lds((gas_ptr)gsrc, (las_ptr)ldst, 16, 0, 0);
}

// ---------------------------------------------------------------------------
// cvt: one-shot bf16 conversion of all GEMM operands (984 blocks):
//   [  0,768): z / z_next / z_next_hat -> zb/znb/znhb   (256 blocks each)
//   [768,896): W2 -> w2b
//   [896,968): W1 [576][512] -> w1t bf16 [512][576] (transpose, LDS-tiled)
//   [968,984): hab = bf16(relu(actions@Wa+ba))  [1024][64]
__global__ __launch_bounds__(256) void cvt_kernel(
    const float* __restrict__ z, const float* __restrict__ z_next,
    const float* __restrict__ z_next_hat, const float* __restrict__ W1,
    const float* __restrict__ W2, const float* __restrict__ actions,
    const float* __restrict__ Wa, const float* __restrict__ ba,
    short* __restrict__ zb, short* __restrict__ znb, short* __restrict__ znhb,
    short* __restrict__ w1t, short* __restrict__ w2b, short* __restrict__ hab)
{
    const int id = blockIdx.x, tid = threadIdx.x;
    if (id < 896) {   // elementwise cvt, 2048 elems/block
        const float* src; short* dst; int local;
        if (id < 256)      { src = z;          dst = zb;   local = id; }
        else if (id < 512) { src = z_next;     dst = znb;  local = id - 256; }
        else if (id < 768) { src = z_next_hat; dst = znhb; local = id - 512; }
        else               { src = W2;         dst = w2b;  local = id - 768; }
        int i8 = local * 2048 + tid * 8;
        float4 x0 = *(const float4*)&src[i8];
        float4 x1 = *(const float4*)&src[i8 + 4];
        short8 h; cvt8rn(x0, x1, h);
        *(short8*)&dst[i8] = h;
    } else if (id < 968) {   // W1 transpose tile -> bf16
        __shared__ float L[64][68];
        int local = id - 896, kt = local >> 3, nt = local & 7;
#pragma unroll
        for (int i = 0; i < 4; ++i) {
            int f = tid + i * 256;
            int r = f >> 4, c4 = (f & 15) << 2;
            *(float4*)&L[r][c4] = *(const float4*)&W1[(kt * 64 + r) * 512 + nt * 64 + c4];
        }
        __syncthreads();
#pragma unroll
        for (int i = 0; i < 4; ++i) {
            int f = tid + i * 256;
            int r = f >> 4, c4 = (f & 15) << 2;
            short4b o = {bf16rn(L[c4][r]), bf16rn(L[c4 + 1][r]),
                         bf16rn(L[c4 + 2][r]), bf16rn(L[c4 + 3][r])};
            *(short4b*)&w1t[(nt * 64 + r) * 576 + kt * 64 + c4] = o;
        }
    } else {                 // ha tile -> bf16
        __shared__ float sWa[A_DIM * 64];
        __shared__ float sba[64];
        int j0 = (id - 968) * 64;
        for (int i = tid; i < A_DIM * 64; i += 256) sWa[i] = Wa[i];
        if (tid < 64) sba[tid] = ba[tid];
        __syncthreads();
        int r = tid >> 2, c0 = (tid & 3) * 16;
        float4 a0 = *(const float4*)&actions[(j0 + r) * A_DIM + 0];
        float4 a1 = *(const float4*)&actions[(j0 + r) * A_DIM + 4];
        float av[8] = {a0.x, a0.y, a0.z, a0.w, a1.x, a1.y, a1.z, a1.w};
        float o[16];
#pragma unroll
        for (int c = 0; c < 16; ++c) o[c] = sba[c0 + c];
#pragma unroll
        for (int k = 0; k < A_DIM; ++k)
#pragma unroll
            for (int c = 0; c < 16; ++c) o[c] += av[k] * sWa[k * 64 + c0 + c];
#pragma unroll
        for (int c = 0; c < 16; c += 4) {
            short4b h = {bf16rn(fmaxf(o[c], 0.f)),     bf16rn(fmaxf(o[c + 1], 0.f)),
                         bf16rn(fmaxf(o[c + 2], 0.f)), bf16rn(fmaxf(o[c + 3], 0.f))};
            *(short4b*)&hab[(j0 + r) * 64 + c0 + c] = h;
        }
    }
}

// ---------------------------------------------------------------------------
// mm v8: 128x128-tile BK=64 NT MFMA GEMM on pre-converted bf16 operands,
// global_load_lds width-16 staging (the proven step-3 structure) with
// source-side XOR pre-swizzle (linear LDS dest + inverse-swizzled global
// source + sw() on the ds_read side) -> bank-conflict-free fragment reads.
// 160 blocks:
//   [  0, 64): sim = znb @ znhb^T  [1024x1024 K=512]
//   [ 64, 96): u   = zb @ w1t[:, :512]^T + b1 [1024x512 K=512]
//   [ 96,128): v   = znb @ w2b^T   [1024x512 K=512]
//   [128,160): g   = hab @ w1t[:, 512:]^T    [1024x512 K=64]
__global__ __launch_bounds__(256, 2) void mm_kernel(
    const short* __restrict__ zb, const short* __restrict__ znb,
    const short* __restrict__ znhb, const short* __restrict__ w1t,
    const short* __restrict__ w2b, const short* __restrict__ hab,
    const float* __restrict__ b1,
    float* __restrict__ sim, float* __restrict__ u, float* __restrict__ v,
    float* __restrict__ g)
{
    __shared__ __align__(16) short Ah[128 * 64], Bh[128 * 64];   // 16 KB each

    const int id = blockIdx.x;
    const int tid = threadIdx.x;

    const short* A; const short* B; const float* bias = nullptr;
    float* C; int N, K, lda, ldb, bm0, bn0;
    if (id < 64) {
        bm0 = (id >> 3) * 128; bn0 = (id & 7) * 128;
        A = znb; lda = 512; B = znhb; ldb = 512; C = sim; N = 1024; K = 512;
    } else if (id < 96) {
        int t = id - 64; bm0 = (t >> 2) * 128; bn0 = (t & 3) * 128;
        A = zb; lda = 512; B = w1t; ldb = 576; C = u; N = 512; K = 512; bias = b1;
    } else if (id < 128) {
        int t = id - 96; bm0 = (t >> 2) * 128; bn0 = (t & 3) * 128;
        A = znb; lda = 512; B = w2b; ldb = 512; C = v; N = 512; K = 512;
    } else {
        int t = id - 128; bm0 = (t >> 2) * 128; bn0 = (t & 3) * 128;
        A = hab; lda = 64; B = w1t + 512; ldb = 576; C = g; N = 512; K = 64;
    }

    const int lane = tid & 63, wv = tid >> 6;
    const int lm = lane & 15, lq = lane >> 4;
    const int wr = (wv >> 1) * 64, wc = (wv & 1) * 64;
    short8* A8 = (short8*)Ah; short8* B8 = (short8*)Bh;
    f32x4 acc[4][4] = {};

    for (int k0 = 0; k0 < K; k0 += 64) {
        // stage A,B tiles: 4 x 1KB-per-wave async ops each; LDS dest linear,
        // global source inverse-swizzled so sw() reads are conflict-free.
#pragma unroll
        for (int q = 0; q < 4; ++q) {
            int f = q * 256 + tid;           // 0..1023: row = f>>3, unit = f&7
            int row = f >> 3;
            int ug = (f & 7) ^ (row & 7);    // inverse swizzle on the source
            gld_lds16(&A[(bm0 + row) * lda + k0 + ug * 8],
                      &Ah[(q * 256 + wv * 64) * 8]);
            gld_lds16(&B[(bn0 + row) * ldb + k0 + ug * 8],
                      &Bh[(q * 256 + wv * 64) * 8]);
        }
        VMWAIT(0);
        raw_barrier();
#pragma unroll
        for (int kk = 0; kk < 64; kk += 32) {
            int kbi = (kk >> 3) + lq;
            short8 ah[4], bh[4];
#pragma unroll
            for (int i = 0; i < 4; ++i) ah[i] = A8[sw(wr + i * 16 + lm, kbi)];
#pragma unroll
            for (int j = 0; j < 4; ++j) bh[j] = B8[sw(wc + j * 16 + lm, kbi)];
#pragma unroll
            for (int i = 0; i < 4; ++i)
#pragma unroll
                for (int j = 0; j < 4; ++j)
                    acc[i][j] = __builtin_amdgcn_mfma_f32_16x16x32_bf16(ah[i], bh[j], acc[i][j], 0, 0, 0);
        }
        raw_barrier();
    }
    // epilogue: C layout col=lane&15, row=(lane>>4)*4+reg  (verified mapping)
#pragma unroll
    for (int i = 0; i < 4; ++i)
#pragma unroll
        for (int j = 0; j < 4; ++j) {
            int n = bn0 + wc + j * 16 + lm;
            float bb = bias ? bias[n] : 0.0f;
#pragma unroll
            for (int r = 0; r < 4; ++r) {
                int m = bm0 + wr + i * 16 + lq * 4 + r;
                C[m * N + n] = acc[i][j][r] + bb;
            }
        }
}

// ---------------------------------------------------------------------------
// row2 v9: the R3-verified v4 register-ILP loop (1024 blocks, one row/block,
// direct g loads, chunks k=w,w+4,w+8 + wave-0 tail, launch_bounds(256,2))
// WITHOUT the atomic tail (R5's proven win): partials -> pw, reduced by
// final_kernel.  This simple-loop + no-atomic combination was never tested;
// all async-LDS variants measured ~30-50us while this loop's warm R1 repeats
// implied only a few us of compute.
#define LOADC(GA, GB, kk) { \
    const int q0_ = (kk) * 8; \
    _Pragma("unroll") \
    for (int c_ = 0; c_ < 8; ++c_) { \
        int j_ = (b + 1 + q0_ + c_) & (B_SZ - 1); \
        GA[c_] = *(const float4*)&g[j_ * 512 + lane * 4]; \
        GB[c_] = *(const float4*)&g[j_ * 512 + 256 + lane * 4]; \
    } }

#define LOADC3(GA, GB) { \
    _Pragma("unroll") \
    for (int c_ = 0; c_ < 3; ++c_) { \
        int j_ = (b + 97 + c_) & (B_SZ - 1); \
        GA[c_] = *(const float4*)&g[j_ * 512 + lane * 4]; \
        GB[c_] = *(const float4*)&g[j_ * 512 + 256 + lane * 4]; \
    } }

#define DOTC(T, GA, GB, NC) { \
    _Pragma("unroll") \
    for (int c_ = 0; c_ < (NC); ++c_) { \
        float s_ = 0.0f; \
        s_ += fmaxf(ua.x + GA[c_].x, 0.0f) * va.x; \
        s_ += fmaxf(ua.y + GA[c_].y, 0.0f) * va.y; \
        s_ += fmaxf(ua.z + GA[c_].z, 0.0f) * va.z; \
        s_ += fmaxf(ua.w + GA[c_].w, 0.0f) * va.w; \
        s_ += fmaxf(ub.x + GB[c_].x, 0.0f) * vb.x; \
        s_ += fmaxf(ub.y + GB[c_].y, 0.0f) * vb.y; \
        s_ += fmaxf(ub.z + GB[c_].z, 0.0f) * vb.z; \
        s_ += fmaxf(ub.w + GB[c_].w, 0.0f) * vb.w; \
        T[c_] = s_; \
    } }

#define REDST(T, kk, NC) { \
    for (int off_ = 32; off_; off_ >>= 1) { \
        _Pragma("unroll") \
        for (int c_ = 0; c_ < (NC); ++c_) T[c_] += __shfl_down(T[c_], off_); \
    } \
    if (lane == 0) { \
        _Pragma("unroll") \
        for (int c_ = 0; c_ < (NC); ++c_) rn[(kk) * 8 + c_] = c0 + T[c_]; \
    } }

__global__ __launch_bounds__(256, 2) void row2_kernel(
    const float* __restrict__ sim, const float* __restrict__ u,
    const float* __restrict__ v, const float* __restrict__ g,
    const float* __restrict__ z, const float* __restrict__ z_next,
    const float* __restrict__ b2,
    float* __restrict__ pw)
{
    const int b = blockIdx.x;
    const int tid = threadIdx.x;
    const int w = tid >> 6, lane = tid & 63;
    __shared__ float rn[104];      // c0 + neg dot, indexed by s-1
    __shared__ float sred[12];     // [0:4) max, [4:8) expsum, [8:12) count

    // issue all phase-0/phase-2 input loads up front (latency hides in phase 1)
    float4 ua = *(const float4*)&u[b * 512 + lane * 4];
    float4 ub = *(const float4*)&u[b * 512 + 256 + lane * 4];
    float4 va = *(const float4*)&v[b * 512 + lane * 4];
    float4 vb = *(const float4*)&v[b * 512 + 256 + lane * 4];
    float4 s4 = *(const float4*)&sim[b * 1024 + tid * 4];
    float diag = sim[b * 1024 + b];

    // c0 = (z[b]+b2) . z_next[b]   (computed redundantly by each wave)
    float p;
    {
        float4 za = *(const float4*)&z[b * 512 + lane * 4];
        float4 zb4 = *(const float4*)&z[b * 512 + 256 + lane * 4];
        float4 na = *(const float4*)&z_next[b * 512 + lane * 4];
        float4 nb = *(const float4*)&z_next[b * 512 + 256 + lane * 4];
        float4 ca = *(const float4*)&b2[lane * 4];
        float4 cb = *(const float4*)&b2[256 + lane * 4];
        p  = (za.x + ca.x) * na.x + (za.y + ca.y) * na.y + (za.z + ca.z) * na.z + (za.w + ca.w) * na.w;
        p += (zb4.x + cb.x) * nb.x + (zb4.y + cb.y) * nb.y + (zb4.z + cb.z) * nb.z + (zb4.w + cb.w) * nb.w;
    }
    for (int off = 32; off; off >>= 1) p += __shfl_down(p, off);
    const float c0 = __shfl(p, 0);

    // -------- phase 1: negatives, chunks k0=w, k1=w+4, k2=w+8, tail on w0 --
    {
        const int k0 = w, k1 = w + 4, k2 = w + 8;
        float4 gaA[8], gbA[8], gaB[8], gbB[8];
        float tA[8], tB[8];

        LOADC(gaA, gbA, k0);            // 16 loads in flight
        LOADC(gaB, gbB, k1);            // 32 loads in flight
        DOTC(tA, gaA, gbA, 8);          // waits only on buffer A
        LOADC(gaA, gbA, k2);            // refill A while reducing
        REDST(tA, k0, 8);
        DOTC(tB, gaB, gbB, 8);
        if (w == 0) LOADC3(gaB, gbB);   // tail chunk 12 (rows 96..98)
        REDST(tB, k1, 8);
        DOTC(tA, gaA, gbA, 8);
        REDST(tA, k2, 8);
        if (w == 0) {
            DOTC(tB, gaB, gbB, 3);
            REDST(tB, 12, 3);
        }
    }
    __syncthreads();

    // -------- phase 2: softmax + rank, 256 threads x 4 sim entries --------
    float neg = (tid < NNEG) ? rn[tid] : -3.4e38f;

    float m = fmaxf(fmaxf(s4.x, s4.y), fmaxf(s4.z, s4.w));
    m = fmaxf(m, neg);
    for (int off = 32; off; off >>= 1) m = fmaxf(m, __shfl_xor(m, off));
    if (lane == 0) sred[w] = m;
    __syncthreads();
    m = fmaxf(fmaxf(sred[0], sred[1]), fmaxf(sred[2], sred[3]));

    float es = 0.0f; int ck = 0;
    {
        float xs[4] = {s4.x, s4.y, s4.z, s4.w};
#pragma unroll
        for (int c = 0; c < 4; ++c) {
            int j = tid * 4 + c;
            float x = xs[c];
            es += __expf((x - m) * INV_T);
            if (x > diag) ck++;
            else if (j < b && x == diag) ck++;   // tie-break: lower index wins
        }
    }
    if (tid < NNEG) {
        es += __expf((neg - m) * INV_T);
        if (neg > diag) ck++;
    }
    float ckf = (float)ck;
    for (int off = 32; off; off >>= 1) {
        es += __shfl_down(es, off);
        ckf += __shfl_down(ckf, off);
    }
    if (lane == 0) { sred[4 + w] = es; sred[8 + w] = ckf; }
    __syncthreads();
    if (tid == 0) {
        float est = sred[4] + sred[5] + sred[6] + sred[7];
        int ckt = (int)(sred[8] + sred[9] + sred[10] + sred[11]);
        pw[b * 4 + 0] = (m - diag) * INV_T + logf(est);
        pw[b * 4 + 1] = (ckt < 1) ? 1.0f : 0.0f;
        pw[b * 4 + 2] = (ckt < 3) ? 1.0f : 0.0f;
        pw[b * 4 + 3] = (ckt < 10) ? 1.0f : 0.0f;
    }
}

// ---------------------------------------------------------------------------
// final: 1 block x 256 threads, reduce pw[1024][4] -> out[4].
__global__ __launch_bounds__(256) void final_kernel(
    const float* __restrict__ pw, float* __restrict__ out)
{
    __shared__ float red[256];
    const int tid = threadIdx.x;
    const int c = tid & 3;
    float s = 0.0f;
    for (int r = tid >> 2; r < 1024; r += 64) s += pw[r * 4 + c];
    red[tid] = s;
    __syncthreads();
    if (tid < 4) {
        float t = 0.0f;
        for (int q = 0; q < 64; ++q) t += red[tid + q * 4];
        out[tid] = t * (1.0f / (float)B_SZ);
    }
}

// ---------------------------------------------------------------------------
extern "C" void kernel_launch(void* const* d_in, const int* in_sizes, int n_in,
                              void* d_out, int out_size, void* d_ws, size_t ws_size,
                              hipStream_t stream) {
    const float* z          = (const float*)d_in[0];
    const float* z_next     = (const float*)d_in[1];
    const float* z_next_hat = (const float*)d_in[2];
    const float* actions    = (const float*)d_in[3];
    const float* Wa         = (const float*)d_in[4];
    const float* ba         = (const float*)d_in[5];
    const float* W1         = (const float*)d_in[6];
    const float* b1         = (const float*)d_in[7];
    const float* W2         = (const float*)d_in[8];
    const float* b2         = (const float*)d_in[9];
    float* out = (float*)d_out;

    float* ws   = (float*)d_ws;
    float* sim  = ws;                          // 1024*1024
    float* u    = sim + B_SZ * B_SZ;           // 1024*512
    float* v    = u + B_SZ * ZH;               // 1024*512
    float* g    = v + B_SZ * ZH;               // 1024*512
    float* pw   = g + B_SZ * ZH;               // 1024*4
    short* zb   = (short*)(pw + B_SZ * 4);     // bf16 region (16B-aligned)
    short* znb  = zb + B_SZ * Z_DIM;           // 524288
    short* znhb = znb + B_SZ * Z_DIM;
    short* w1t  = znhb + B_SZ * Z_DIM;         // 512*576
    short* w2b  = w1t + 512 * 576;             // 512*512
    short* hab  = w2b + 512 * 512;             // 1024*64

    cvt_kernel<<<984, 256, 0, stream>>>(z, z_next, z_next_hat, W1, W2,
                                        actions, Wa, ba,
                                        zb, znb, znhb, w1t, w2b, hab);
    mm_kernel<<<160, 256, 0, stream>>>(zb, znb, znhb, w1t, w2b, hab, b1,
                                       sim, u, v, g);
    row2_kernel<<<1024, 256, 0, stream>>>(sim, u, v, g, z, z_next, b2, pw);
    final_kernel<<<1, 256, 0, stream>>>(pw, out);
}

// Round 8
// 112.614 us; speedup vs baseline: 1.2115x; 1.0233x over previous
//
#include <hip/hip_runtime.h>
#include <math.h>

#define B_SZ 1024
#define Z_DIM 512
#define A_DIM 8
#define AH 64
#define ZH 512
#define NNEG 99
#define INV_T 10.0f
#define RNP 104   // rnall row pitch

typedef __attribute__((ext_vector_type(8))) short short8;   // 8 bf16 (16 B)
typedef __attribute__((ext_vector_type(4))) short short4b;  // 4 bf16 (8 B)
typedef __attribute__((ext_vector_type(4))) float f32x4;

// fp32 -> bf16 round-to-nearest-even (unbiased; rel err <= 2^-9)
__device__ __forceinline__ short bf16rn(float x) {
    unsigned u = __float_as_uint(x);
    u += 0x7fffu + ((u >> 16) & 1u);
    return (short)(u >> 16);
}
__device__ __forceinline__ void cvt8rn(float4 x0, float4 x1, short8& h) {
    h[0] = bf16rn(x0.x); h[1] = bf16rn(x0.y); h[2] = bf16rn(x0.z); h[3] = bf16rn(x0.w);
    h[4] = bf16rn(x1.x); h[5] = bf16rn(x1.y); h[6] = bf16rn(x1.z); h[7] = bf16rn(x1.w);
}

// XOR-swizzled 16B-unit index into a [rows][8 units] bf16 tile (no padding).
__device__ __forceinline__ int sw(int m, int kb) { return m * 8 + (kb ^ (m & 7)); }

#define VMWAIT(N) asm volatile("s_waitcnt vmcnt(" #N ")" ::: "memory")
__device__ __forceinline__ void raw_barrier() {
    asm volatile("" ::: "memory");
    __builtin_amdgcn_s_barrier();
    asm volatile("" ::: "memory");
}
typedef const __attribute__((address_space(1))) void* gas_ptr;
typedef __attribute__((address_space(3))) void* las_ptr;
__device__ __forceinline__ void gld_lds16(const void* gsrc, void* ldst) {
    __builtin_amdgcn_global_load_lds((gas_ptr)gsrc, (las_ptr)ldst, 16, 0, 0);
}

// ---------------------------------------------------------------------------
// cvt: one-shot bf16 conversion of all GEMM operands (984 blocks):
//   [  0,768): z / z_next / z_next_hat -> zb/znb/znhb   (256 blocks each)
//   [768,896): W2 -> w2b
//   [896,968): W1 [576][512] -> w1t bf16 [512][576] (transpose, LDS-tiled)
//   [968,984): hab = bf16(relu(actions@Wa+ba))  [1024][64]
__global__ __launch_bounds__(256) void cvt_kernel(
    const float* __restrict__ z, const float* __restrict__ z_next,
    const float* __restrict__ z_next_hat, const float* __restrict__ W1,
    const float* __restrict__ W2, const float* __restrict__ actions,
    const float* __restrict__ Wa, const float* __restrict__ ba,
    short* __restrict__ zb, short* __restrict__ znb, short* __restrict__ znhb,
    short* __restrict__ w1t, short* __restrict__ w2b, short* __restrict__ hab)
{
    const int id = blockIdx.x, tid = threadIdx.x;
    if (id < 896) {   // elementwise cvt, 2048 elems/block
        const float* src; short* dst; int local;
        if (id < 256)      { src = z;          dst = zb;   local = id; }
        else if (id < 512) { src = z_next;     dst = znb;  local = id - 256; }
        else if (id < 768) { src = z_next_hat; dst = znhb; local = id - 512; }
        else               { src = W2;         dst = w2b;  local = id - 768; }
        int i8 = local * 2048 + tid * 8;
        float4 x0 = *(const float4*)&src[i8];
        float4 x1 = *(const float4*)&src[i8 + 4];
        short8 h; cvt8rn(x0, x1, h);
        *(short8*)&dst[i8] = h;
    } else if (id < 968) {   // W1 transpose tile -> bf16
        __shared__ float L[64][68];
        int local = id - 896, kt = local >> 3, nt = local & 7;
#pragma unroll
        for (int i = 0; i < 4; ++i) {
            int f = tid + i * 256;
            int r = f >> 4, c4 = (f & 15) << 2;
            *(float4*)&L[r][c4] = *(const float4*)&W1[(kt * 64 + r) * 512 + nt * 64 + c4];
        }
        __syncthreads();
#pragma unroll
        for (int i = 0; i < 4; ++i) {
            int f = tid + i * 256;
            int r = f >> 4, c4 = (f & 15) << 2;
            short4b o = {bf16rn(L[c4][r]), bf16rn(L[c4 + 1][r]),
                         bf16rn(L[c4 + 2][r]), bf16rn(L[c4 + 3][r])};
            *(short4b*)&w1t[(nt * 64 + r) * 576 + kt * 64 + c4] = o;
        }
    } else {                 // ha tile -> bf16
        __shared__ float sWa[A_DIM * 64];
        __shared__ float sba[64];
        int j0 = (id - 968) * 64;
        for (int i = tid; i < A_DIM * 64; i += 256) sWa[i] = Wa[i];
        if (tid < 64) sba[tid] = ba[tid];
        __syncthreads();
        int r = tid >> 2, c0 = (tid & 3) * 16;
        float4 a0 = *(const float4*)&actions[(j0 + r) * A_DIM + 0];
        float4 a1 = *(const float4*)&actions[(j0 + r) * A_DIM + 4];
        float av[8] = {a0.x, a0.y, a0.z, a0.w, a1.x, a1.y, a1.z, a1.w};
        float o[16];
#pragma unroll
        for (int c = 0; c < 16; ++c) o[c] = sba[c0 + c];
#pragma unroll
        for (int k = 0; k < A_DIM; ++k)
#pragma unroll
            for (int c = 0; c < 16; ++c) o[c] += av[k] * sWa[k * 64 + c0 + c];
#pragma unroll
        for (int c = 0; c < 16; c += 4) {
            short4b h = {bf16rn(fmaxf(o[c], 0.f)),     bf16rn(fmaxf(o[c + 1], 0.f)),
                         bf16rn(fmaxf(o[c + 2], 0.f)), bf16rn(fmaxf(o[c + 3], 0.f))};
            *(short4b*)&hab[(j0 + r) * 64 + c0 + c] = h;
        }
    }
}

// ---------------------------------------------------------------------------
// mm v8 (unchanged, verified R7): 128x128-tile BK=64 NT MFMA GEMM on bf16,
// global_load_lds width-16 staging, source-side XOR pre-swizzle.  160 blocks.
__global__ __launch_bounds__(256, 2) void mm_kernel(
    const short* __restrict__ zb, const short* __restrict__ znb,
    const short* __restrict__ znhb, const short* __restrict__ w1t,
    const short* __restrict__ w2b, const short* __restrict__ hab,
    const float* __restrict__ b1,
    float* __restrict__ sim, float* __restrict__ u, float* __restrict__ v,
    float* __restrict__ g)
{
    __shared__ __align__(16) short Ah[128 * 64], Bh[128 * 64];   // 16 KB each

    const int id = blockIdx.x;
    const int tid = threadIdx.x;

    const short* A; const short* B; const float* bias = nullptr;
    float* C; int N, K, lda, ldb, bm0, bn0;
    if (id < 64) {
        bm0 = (id >> 3) * 128; bn0 = (id & 7) * 128;
        A = znb; lda = 512; B = znhb; ldb = 512; C = sim; N = 1024; K = 512;
    } else if (id < 96) {
        int t = id - 64; bm0 = (t >> 2) * 128; bn0 = (t & 3) * 128;
        A = zb; lda = 512; B = w1t; ldb = 576; C = u; N = 512; K = 512; bias = b1;
    } else if (id < 128) {
        int t = id - 96; bm0 = (t >> 2) * 128; bn0 = (t & 3) * 128;
        A = znb; lda = 512; B = w2b; ldb = 512; C = v; N = 512; K = 512;
    } else {
        int t = id - 128; bm0 = (t >> 2) * 128; bn0 = (t & 3) * 128;
        A = hab; lda = 64; B = w1t + 512; ldb = 576; C = g; N = 512; K = 64;
    }

    const int lane = tid & 63, wv = tid >> 6;
    const int lm = lane & 15, lq = lane >> 4;
    const int wr = (wv >> 1) * 64, wc = (wv & 1) * 64;
    short8* A8 = (short8*)Ah; short8* B8 = (short8*)Bh;
    f32x4 acc[4][4] = {};

    for (int k0 = 0; k0 < K; k0 += 64) {
#pragma unroll
        for (int q = 0; q < 4; ++q) {
            int f = q * 256 + tid;           // 0..1023: row = f>>3, unit = f&7
            int row = f >> 3;
            int ug = (f & 7) ^ (row & 7);    // inverse swizzle on the source
            gld_lds16(&A[(bm0 + row) * lda + k0 + ug * 8],
                      &Ah[(q * 256 + wv * 64) * 8]);
            gld_lds16(&B[(bn0 + row) * ldb + k0 + ug * 8],
                      &Bh[(q * 256 + wv * 64) * 8]);
        }
        VMWAIT(0);
        raw_barrier();
#pragma unroll
        for (int kk = 0; kk < 64; kk += 32) {
            int kbi = (kk >> 3) + lq;
            short8 ah[4], bh[4];
#pragma unroll
            for (int i = 0; i < 4; ++i) ah[i] = A8[sw(wr + i * 16 + lm, kbi)];
#pragma unroll
            for (int j = 0; j < 4; ++j) bh[j] = B8[sw(wc + j * 16 + lm, kbi)];
#pragma unroll
            for (int i = 0; i < 4; ++i)
#pragma unroll
                for (int j = 0; j < 4; ++j)
                    acc[i][j] = __builtin_amdgcn_mfma_f32_16x16x32_bf16(ah[i], bh[j], acc[i][j], 0, 0, 0);
        }
        raw_barrier();
    }
#pragma unroll
    for (int i = 0; i < 4; ++i)
#pragma unroll
        for (int j = 0; j < 4; ++j) {
            int n = bn0 + wc + j * 16 + lm;
            float bb = bias ? bias[n] : 0.0f;
#pragma unroll
            for (int r = 0; r < 4; ++r) {
                int m = bm0 + wr + i * 16 + lq * 4 + r;
                C[m * N + n] = acc[i][j][r] + bb;
            }
        }
}

// ---------------------------------------------------------------------------
// neg v10: pure streaming negatives — grid (1024 b, 13 s-octets) x 64 thr.
// No LDS, no barriers, no shared state; each wave: load u/v row b + 8 g rows,
// 8 independent dot chains, shuffle-reduce, store raw dots to rnall.
// __launch_bounds__(64,4) caps occupancy pressure so the 16-float4 buffer
// stays in registers (R1 lesson: default budget re-serializes the loads).
// This isolates the 35+us mystery: if THIS is still slow, the wall is the
// g read path (203MB L2/L3 re-reads), not kernel structure.
__global__ __launch_bounds__(64, 4) void neg_kernel(
    const float* __restrict__ u, const float* __restrict__ v,
    const float* __restrict__ g, float* __restrict__ rnall)
{
    const int b = blockIdx.x, t = blockIdx.y;
    const int lane = threadIdx.x;
    const int s0 = 1 + t * 8;               // s = s0..s0+7 (valid while <= 99)

    float4 ga[8], gb[8];
#pragma unroll
    for (int c = 0; c < 8; ++c) {
        int j = (b + s0 + c) & (B_SZ - 1);  // loads always in-bounds
        ga[c] = *(const float4*)&g[j * 512 + lane * 4];
        gb[c] = *(const float4*)&g[j * 512 + 256 + lane * 4];
    }
    float4 ua = *(const float4*)&u[b * 512 + lane * 4];
    float4 ub = *(const float4*)&u[b * 512 + 256 + lane * 4];
    float4 va = *(const float4*)&v[b * 512 + lane * 4];
    float4 vb = *(const float4*)&v[b * 512 + 256 + lane * 4];

    float d[8];
#pragma unroll
    for (int c = 0; c < 8; ++c) {
        float s = 0.0f;
        s += fmaxf(ua.x + ga[c].x, 0.0f) * va.x;
        s += fmaxf(ua.y + ga[c].y, 0.0f) * va.y;
        s += fmaxf(ua.z + ga[c].z, 0.0f) * va.z;
        s += fmaxf(ua.w + ga[c].w, 0.0f) * va.w;
        s += fmaxf(ub.x + gb[c].x, 0.0f) * vb.x;
        s += fmaxf(ub.y + gb[c].y, 0.0f) * vb.y;
        s += fmaxf(ub.z + gb[c].z, 0.0f) * vb.z;
        s += fmaxf(ub.w + gb[c].w, 0.0f) * vb.w;
        d[c] = s;
    }
    for (int off = 32; off; off >>= 1) {
#pragma unroll
        for (int c = 0; c < 8; ++c) d[c] += __shfl_down(d[c], off);
    }
    if (lane == 0) {
#pragma unroll
        for (int c = 0; c < 8; ++c)
            if (s0 + c <= NNEG) rnall[b * RNP + s0 + c - 1] = d[c];
    }
}

// ---------------------------------------------------------------------------
// smax v10: 1024 blocks x 256 threads — softmax + rank for row b.
// Computes c0 = (z[b]+b2).z_next[b] in-block, reads sim row + rnall row,
// writes 4 partials to pw (no atomics; final_kernel reduces).
__global__ __launch_bounds__(256) void smax_kernel(
    const float* __restrict__ sim, const float* __restrict__ rnall,
    const float* __restrict__ z, const float* __restrict__ z_next,
    const float* __restrict__ b2, float* __restrict__ pw)
{
    const int b = blockIdx.x;
    const int tid = threadIdx.x;
    const int w = tid >> 6, lane = tid & 63;
    __shared__ float sred[12];     // [0:4) c0/max partials, [4:8) es, [8:12) ck

    float4 s4 = *(const float4*)&sim[b * 1024 + tid * 4];
    float rawn = (tid < NNEG) ? rnall[b * RNP + tid] : 0.0f;
    float diag = sim[b * 1024 + b];

    // c0: each thread covers 2 elements
    float2 z2 = *(const float2*)&z[b * 512 + tid * 2];
    float2 n2 = *(const float2*)&z_next[b * 512 + tid * 2];
    float2 c2 = *(const float2*)&b2[tid * 2];
    float p = (z2.x + c2.x) * n2.x + (z2.y + c2.y) * n2.y;
    for (int off = 32; off; off >>= 1) p += __shfl_down(p, off);
    if (lane == 0) sred[w] = p;
    __syncthreads();
    const float c0 = sred[0] + sred[1] + sred[2] + sred[3];
    __syncthreads();

    float neg = (tid < NNEG) ? (rawn + c0) : -3.4e38f;

    float m = fmaxf(fmaxf(s4.x, s4.y), fmaxf(s4.z, s4.w));
    m = fmaxf(m, neg);
    for (int off = 32; off; off >>= 1) m = fmaxf(m, __shfl_xor(m, off));
    if (lane == 0) sred[w] = m;
    __syncthreads();
    m = fmaxf(fmaxf(sred[0], sred[1]), fmaxf(sred[2], sred[3]));

    float es = 0.0f; int ck = 0;
    {
        float xs[4] = {s4.x, s4.y, s4.z, s4.w};
#pragma unroll
        for (int c = 0; c < 4; ++c) {
            int j = tid * 4 + c;
            float x = xs[c];
            es += __expf((x - m) * INV_T);
            if (x > diag) ck++;
            else if (j < b && x == diag) ck++;   // tie-break: lower index wins
        }
    }
    if (tid < NNEG) {
        es += __expf((neg - m) * INV_T);
        if (neg > diag) ck++;
    }
    float ckf = (float)ck;
    for (int off = 32; off; off >>= 1) {
        es += __shfl_down(es, off);
        ckf += __shfl_down(ckf, off);
    }
    if (lane == 0) { sred[4 + w] = es; sred[8 + w] = ckf; }
    __syncthreads();
    if (tid == 0) {
        float est = sred[4] + sred[5] + sred[6] + sred[7];
        int ckt = (int)(sred[8] + sred[9] + sred[10] + sred[11]);
        pw[b * 4 + 0] = (m - diag) * INV_T + logf(est);
        pw[b * 4 + 1] = (ckt < 1) ? 1.0f : 0.0f;
        pw[b * 4 + 2] = (ckt < 3) ? 1.0f : 0.0f;
        pw[b * 4 + 3] = (ckt < 10) ? 1.0f : 0.0f;
    }
}

// ---------------------------------------------------------------------------
// final: 1 block x 256 threads, reduce pw[1024][4] -> out[4].
__global__ __launch_bounds__(256) void final_kernel(
    const float* __restrict__ pw, float* __restrict__ out)
{
    __shared__ float red[256];
    const int tid = threadIdx.x;
    const int c = tid & 3;
    float s = 0.0f;
    for (int r = tid >> 2; r < 1024; r += 64) s += pw[r * 4 + c];
    red[tid] = s;
    __syncthreads();
    if (tid < 4) {
        float t = 0.0f;
        for (int q = 0; q < 64; ++q) t += red[tid + q * 4];
        out[tid] = t * (1.0f / (float)B_SZ);
    }
}

// ---------------------------------------------------------------------------
extern "C" void kernel_launch(void* const* d_in, const int* in_sizes, int n_in,
                              void* d_out, int out_size, void* d_ws, size_t ws_size,
                              hipStream_t stream) {
    const float* z          = (const float*)d_in[0];
    const float* z_next     = (const float*)d_in[1];
    const float* z_next_hat = (const float*)d_in[2];
    const float* actions    = (const float*)d_in[3];
    const float* Wa         = (const float*)d_in[4];
    const float* ba         = (const float*)d_in[5];
    const float* W1         = (const float*)d_in[6];
    const float* b1         = (const float*)d_in[7];
    const float* W2         = (const float*)d_in[8];
    const float* b2         = (const float*)d_in[9];
    float* out = (float*)d_out;

    float* ws    = (float*)d_ws;
    float* sim   = ws;                          // 1024*1024
    float* u     = sim + B_SZ * B_SZ;           // 1024*512
    float* v     = u + B_SZ * ZH;               // 1024*512
    float* g     = v + B_SZ * ZH;               // 1024*512
    float* pw    = g + B_SZ * ZH;               // 1024*4
    float* rnall = pw + B_SZ * 4;               // 1024*104
    short* zb    = (short*)(rnall + B_SZ * RNP);
    short* znb   = zb + B_SZ * Z_DIM;
    short* znhb  = znb + B_SZ * Z_DIM;
    short* w1t   = znhb + B_SZ * Z_DIM;         // 512*576
    short* w2b   = w1t + 512 * 576;             // 512*512
    short* hab   = w2b + 512 * 512;             // 1024*64

    cvt_kernel<<<984, 256, 0, stream>>>(z, z_next, z_next_hat, W1, W2,
                                        actions, Wa, ba,
                                        zb, znb, znhb, w1t, w2b, hab);
    mm_kernel<<<160, 256, 0, stream>>>(zb, znb, znhb, w1t, w2b, hab, b1,
                                       sim, u, v, g);
    neg_kernel<<<dim3(B_SZ, 13), 64, 0, stream>>>(u, v, g, rnall);
    smax_kernel<<<B_SZ, 256, 0, stream>>>(sim, rnall, z, z_next, b2, pw);
    final_kernel<<<1, 256, 0, stream>>>(pw, out);
}